// Round 1
// baseline (602.796 us; speedup 1.0000x reference)
//
#include <hip/hip_runtime.h>
#include <hip/hip_bf16.h>
#include <math.h>

// Problem constants
#define B 8
#define L 128
#define D 200
#define NROWS 2048          // 2 sequences * B * L
#define PAD_ID 1
#define NEG_INF (-1e13f)

// ---------------- Generic tiled f32 GEMM ----------------
// C[M,N] = act( A[M,K] @ W[K,N] + bias ), C row stride ldc, column offset coff.
// GATHER=1: A row r = emb[ ids(r) ], ids(r) = r<1024 ? x1[r] : x2[r-1024]
// ACT: 0 = none, 1 = ELU
#define TM 64
#define TN 64
#define KC 16

template<int ACT, int GATHER>
__global__ __launch_bounds__(256)
void gemm_k(const float* __restrict__ A,
            const int* __restrict__ x1, const int* __restrict__ x2,
            const float* __restrict__ emb,
            const float* __restrict__ W, const float* __restrict__ bias,
            float* __restrict__ C, int M, int N, int K, int ldc, int coff)
{
    __shared__ float As[KC][TM + 1];
    __shared__ float Bs[KC][TN + 1];
    const int bn = blockIdx.x, bm = blockIdx.y;
    const int row0 = bm * TM, col0 = bn * TN;
    const int tid = threadIdx.x;
    const int tx = tid & 15, ty = tid >> 4;

    float acc[4][4] = {};
    const int nK = (K + KC - 1) / KC;
    for (int kc = 0; kc < nK; ++kc) {
        const int k0 = kc * KC;
        // Stage A tile: 64 rows x 16 k
        #pragma unroll
        for (int t = 0; t < 4; ++t) {
            int idx = tid + 256 * t;
            int m = idx >> 4, k = idx & 15;
            int row = row0 + m, kk = k0 + k;
            float v = 0.f;
            if (row < M && kk < K) {
                if (GATHER) {
                    int id = (row < 1024) ? x1[row] : x2[row - 1024];
                    v = emb[id * K + kk];
                } else {
                    v = A[row * K + kk];
                }
            }
            As[k][m] = v;
        }
        // Stage W tile: 16 k x 64 n
        #pragma unroll
        for (int t = 0; t < 4; ++t) {
            int idx = tid + 256 * t;
            int k = idx >> 6, n = idx & 63;
            int kk = k0 + k, col = col0 + n;
            float v = 0.f;
            if (kk < K && col < N) v = W[kk * N + col];
            Bs[k][n] = v;
        }
        __syncthreads();
        #pragma unroll
        for (int k = 0; k < KC; ++k) {
            float a[4], w[4];
            #pragma unroll
            for (int r = 0; r < 4; ++r) a[r] = As[k][ty * 4 + r];
            #pragma unroll
            for (int r = 0; r < 4; ++r) w[r] = Bs[k][tx * 4 + r];
            #pragma unroll
            for (int i = 0; i < 4; ++i)
                #pragma unroll
                for (int j = 0; j < 4; ++j)
                    acc[i][j] = fmaf(a[i], w[j], acc[i][j]);
        }
        __syncthreads();
    }
    #pragma unroll
    for (int i = 0; i < 4; ++i) {
        int row = row0 + ty * 4 + i;
        if (row >= M) continue;
        #pragma unroll
        for (int j = 0; j < 4; ++j) {
            int col = col0 + tx * 4 + j;
            if (col >= N) continue;
            float v = acc[i][j];
            if (bias) v += bias[col];
            if (ACT == 1) v = (v > 0.f) ? v : expm1f(v);
            C[row * ldc + coff + col] = v;
        }
    }
}

// ---------------- Fused attention: scores -> softmax -> weighted sum ----------------
// One block per global row (seq*B*L). Thread d (<200) handles dim d.
// Computes s_fw[row,d], s_bw[row,d].
__global__ __launch_bounds__(256)
void attn_k(const float* __restrict__ h, const float* __restrict__ h1,
            const float* __restrict__ h2, const float* __restrict__ bvec,
            const float* __restrict__ cptr,
            const int* __restrict__ x1, const int* __restrict__ x2,
            float* __restrict__ s_fw, float* __restrict__ s_bw)
{
    const int blk = blockIdx.x;          // 0..2047
    const int i = blk & 127;             // query position
    const int base = blk & ~127;         // row of key 0 for this (seq,b)
    const int d = threadIdx.x;
    const int* ids = (blk < 1024) ? x1 : x2;
    const int loc_q = blk & 1023;        // index into this sequence's id array
    const int loc_k0 = base & 1023;

    const float cval = cptr[0];
    const float LOG2E = 1.4426950408889634f;
    const float k1 = 2.0f * LOG2E / cval;     // exp2(k1*x) = exp(2x/c)
    const bool mask_i = (ids[loc_q] == PAD_ID);

    float p = 0.f;
    if (d < D) p = h1[blk * D + d] + bvec[d];

    float l_fw = 0.f, l_bw = 0.f, a_fw = 0.f, a_bw = 0.f, hsum = 0.f;

    for (int j = 0; j < 128; ++j) {
        const bool mask_j = (ids[loc_k0 + j] == PAD_ID);
        const bool pad = mask_i || mask_j;
        float h2j = 0.f, hj = 0.f;
        if (d < D) {
            h2j = h2[(base + j) * D + d];
            hj  = h[(base + j) * D + d];
        }
        // t_raw = c * tanh((p + h2j)/c) = c - 2c / (exp(2(p+h2j)/c) + 1)
        float e2 = __builtin_amdgcn_exp2f((p + h2j) * k1);
        float traw = fmaf(-2.0f * cval, __builtin_amdgcn_rcpf(e2 + 1.0f), cval);
        float tfw = (pad || (j <= i)) ? NEG_INF : traw;
        float tbw = (pad || (i <= j)) ? NEG_INF : traw;
        float efw = __builtin_amdgcn_exp2f(tfw * LOG2E);
        float ebw = __builtin_amdgcn_exp2f(tbw * LOG2E);
        l_fw += efw; a_fw = fmaf(efw, hj, a_fw);
        l_bw += ebw; a_bw = fmaf(ebw, hj, a_bw);
        hsum += hj;
    }
    if (d < D) {
        float sf = (l_fw > 0.f) ? (a_fw / l_fw) : (hsum * (1.0f / 128.0f));
        float sb = (l_bw > 0.f) ? (a_bw / l_bw) : (hsum * (1.0f / 128.0f));
        s_fw[blk * D + d] = sf;
        s_bw[blk * D + d] = sb;
    }
}

// ---------------- Fusion gate + u assembly ----------------
// u halves currently hold g = s @ Wf1 (from GEMM). Compute
// f = sigmoid(g + hf2), u = f*h + (1-f)*s, in place.
__global__ __launch_bounds__(256)
void ucomb_k(const float* __restrict__ h, const float* __restrict__ hf2,
             const float* __restrict__ s_fw, const float* __restrict__ s_bw,
             float* __restrict__ u)
{
    int idx = blockIdx.x * 256 + threadIdx.x;
    if (idx >= NROWS * D) return;
    int row = idx / D, d = idx - row * D;
    float g_fw = u[row * 400 + d];
    float g_bw = u[row * 400 + 200 + d];
    float hv = h[idx], hf = hf2[idx];
    float sf = s_fw[idx], sb = s_bw[idx];
    float ffw = 1.0f / (1.0f + __expf(-(g_fw + hf)));
    float fbw = 1.0f / (1.0f + __expf(-(g_bw + hf)));
    u[row * 400 + d]       = ffw * hv + (1.f - ffw) * sf;
    u[row * 400 + 200 + d] = fbw * hv + (1.f - fbw) * sb;
}

// ---------------- Per-(seq,b) weighted sum over L ----------------
__global__ __launch_bounds__(256)
void reduce_k(const float* __restrict__ u, const float* __restrict__ atts,
              float* __restrict__ blockvec)
{
    int sb = blockIdx.x;                  // 0..15
    for (int n = threadIdx.x; n < 400; n += 256) {
        float acc = 0.f;
        for (int l = 0; l < 128; ++l) {
            int r = sb * 128 + l;
            acc = fmaf(u[r * 400 + n], atts[r * 400 + n], acc);
        }
        blockvec[sb * 400 + n] = acc;
    }
}

// ---------------- Final MLP ----------------
__global__ __launch_bounds__(256)
void final1_k(const float* __restrict__ blockvec, const float* __restrict__ F1w,
              const float* __restrict__ F1b, float* __restrict__ t1)
{
    int b = blockIdx.x;                   // 0..7
    int n = threadIdx.x;                  // 0..255
    const float* cv = blockvec + b * 400;
    const float* rv = blockvec + (8 + b) * 400;
    float acc = (n < D) ? F1b[n] : 0.f;
    for (int k = 0; k < 400; ++k) {
        float cvk = cv[k], rvk = rv[k];
        if (n < D) {
            acc = fmaf(cvk,       F1w[k * D + n],          acc);
            acc = fmaf(rvk,       F1w[(400 + k) * D + n],  acc);
            acc = fmaf(cvk - rvk, F1w[(800 + k) * D + n],  acc);
            acc = fmaf(cvk * rvk, F1w[(1200 + k) * D + n], acc);
        }
    }
    if (n < D) t1[b * D + n] = fmaxf(acc, 0.f);
}

__global__ __launch_bounds__(64)
void final2_k(const float* __restrict__ t1, const float* __restrict__ F2w,
              const float* __restrict__ F2b, float* __restrict__ y)
{
    int b = blockIdx.x;
    int t = threadIdx.x;
    float acc = 0.f;
    for (int n = t; n < D; n += 64) acc = fmaf(t1[b * D + n], F2w[n], acc);
    #pragma unroll
    for (int off = 32; off; off >>= 1) acc += __shfl_down(acc, off);
    if (t == 0) y[b] = acc + F2b[0];
}

extern "C" void kernel_launch(void* const* d_in, const int* in_sizes, int n_in,
                              void* d_out, int out_size, void* d_ws, size_t ws_size,
                              hipStream_t stream)
{
    const int*   x1    = (const int*)d_in[0];
    const int*   x2    = (const int*)d_in[1];
    const float* emb   = (const float*)d_in[2];
    const float* Wh_w  = (const float*)d_in[3];
    const float* Wh_b  = (const float*)d_in[4];
    const float* W1_w  = (const float*)d_in[5];
    const float* W2_w  = (const float*)d_in[6];
    const float* bvec  = (const float*)d_in[7];
    const float* cptr  = (const float*)d_in[8];
    const float* Wf1_w = (const float*)d_in[9];
    const float* Wf2_w = (const float*)d_in[10];
    const float* Wf2_b = (const float*)d_in[11];
    const float* Ws1_w = (const float*)d_in[12];
    const float* Ws1_b = (const float*)d_in[13];
    const float* Ws_w  = (const float*)d_in[14];
    const float* Ws_b  = (const float*)d_in[15];
    const float* F1_w  = (const float*)d_in[16];
    const float* F1_b  = (const float*)d_in[17];
    const float* F2_w  = (const float*)d_in[18];
    const float* F2_b  = (const float*)d_in[19];
    float* y = (float*)d_out;

    float* ws = (float*)d_ws;
    float* h    = ws;
    float* h1   = h    + NROWS * D;
    float* h2   = h1   + NROWS * D;
    float* hf2  = h2   + NROWS * D;
    float* sfw  = hf2  + NROWS * D;
    float* sbw  = sfw  + NROWS * D;
    float* u    = sbw  + NROWS * D;       // NROWS*400
    float* v1   = u    + NROWS * 400;
    float* atts = v1   + NROWS * 400;
    float* bv   = atts + NROWS * 400;     // 16*400
    float* t1   = bv   + 16 * 400;        // 8*200

    dim3 blk(256);
    dim3 g200((200 + TN - 1) / TN, NROWS / TM);   // 4 x 32
    dim3 g400((400 + TN - 1) / TN, NROWS / TM);   // 7 x 32

    // 1. h = elu(emb[x] @ Wh + Wh_b)
    gemm_k<1, 1><<<g200, blk, 0, stream>>>(nullptr, x1, x2, emb, Wh_w, Wh_b,
                                           h, NROWS, D, D, D, 0);
    // 2-4. h1 = h@W1, h2 = h@W2, hf2 = h@Wf2 + Wf2_b
    gemm_k<0, 0><<<g200, blk, 0, stream>>>(h, nullptr, nullptr, nullptr, W1_w, nullptr,
                                           h1, NROWS, D, D, D, 0);
    gemm_k<0, 0><<<g200, blk, 0, stream>>>(h, nullptr, nullptr, nullptr, W2_w, nullptr,
                                           h2, NROWS, D, D, D, 0);
    gemm_k<0, 0><<<g200, blk, 0, stream>>>(h, nullptr, nullptr, nullptr, Wf2_w, Wf2_b,
                                           hf2, NROWS, D, D, D, 0);
    // 5. fused attention (both directions)
    attn_k<<<dim3(NROWS), blk, 0, stream>>>(h, h1, h2, bvec, cptr, x1, x2, sfw, sbw);
    // 6-7. g = s @ Wf1 into u halves
    gemm_k<0, 0><<<g200, blk, 0, stream>>>(sfw, nullptr, nullptr, nullptr, Wf1_w, nullptr,
                                           u, NROWS, D, D, 400, 0);
    gemm_k<0, 0><<<g200, blk, 0, stream>>>(sbw, nullptr, nullptr, nullptr, Wf1_w, nullptr,
                                           u, NROWS, D, D, 400, 200);
    // 8. u = f*h + (1-f)*s
    ucomb_k<<<dim3(NROWS * D / 256), blk, 0, stream>>>(h, hf2, sfw, sbw, u);
    // 9. v1 = elu(u @ Ws1 + Ws1_b)
    gemm_k<1, 0><<<g400, blk, 0, stream>>>(u, nullptr, nullptr, nullptr, Ws1_w, Ws1_b,
                                           v1, NROWS, 400, 400, 400, 0);
    // 10. atts = v1 @ Ws + Ws_b
    gemm_k<0, 0><<<g400, blk, 0, stream>>>(v1, nullptr, nullptr, nullptr, Ws_w, Ws_b,
                                           atts, NROWS, 400, 400, 400, 0);
    // 11. blockvec = sum_l u * atts
    reduce_k<<<dim3(16), blk, 0, stream>>>(u, atts, bv);
    // 12-13. final MLP
    final1_k<<<dim3(8), blk, 0, stream>>>(bv, F1_w, F1_b, t1);
    final2_k<<<dim3(8), dim3(64), 0, stream>>>(t1, F2_w, F2_b, y);
}

// Round 2
// 465.006 us; speedup vs baseline: 1.2963x; 1.2963x over previous
//
#include <hip/hip_runtime.h>
#include <hip/hip_bf16.h>
#include <math.h>

// Problem constants
#define B 8
#define L 128
#define D 200
#define NROWS 2048          // 2 sequences * B * L
#define PAD_ID 1
#define NEG_INF (-1e13f)

// ---------------- Generic tiled f32 GEMM ----------------
#define TM 64
#define TN 64
#define KC 16

template<int ACT, int GATHER>
__global__ __launch_bounds__(256)
void gemm_k(const float* __restrict__ A,
            const int* __restrict__ x1, const int* __restrict__ x2,
            const float* __restrict__ emb,
            const float* __restrict__ W, const float* __restrict__ bias,
            float* __restrict__ C, int M, int N, int K, int ldc, int coff)
{
    __shared__ float As[KC][TM + 1];
    __shared__ float Bs[KC][TN + 1];
    const int bn = blockIdx.x, bm = blockIdx.y;
    const int row0 = bm * TM, col0 = bn * TN;
    const int tid = threadIdx.x;
    const int tx = tid & 15, ty = tid >> 4;

    float acc[4][4] = {};
    const int nK = (K + KC - 1) / KC;
    for (int kc = 0; kc < nK; ++kc) {
        const int k0 = kc * KC;
        #pragma unroll
        for (int t = 0; t < 4; ++t) {
            int idx = tid + 256 * t;
            int m = idx >> 4, k = idx & 15;
            int row = row0 + m, kk = k0 + k;
            float v = 0.f;
            if (row < M && kk < K) {
                if (GATHER) {
                    int id = (row < 1024) ? x1[row] : x2[row - 1024];
                    v = emb[id * K + kk];
                } else {
                    v = A[row * K + kk];
                }
            }
            As[k][m] = v;
        }
        #pragma unroll
        for (int t = 0; t < 4; ++t) {
            int idx = tid + 256 * t;
            int k = idx >> 6, n = idx & 63;
            int kk = k0 + k, col = col0 + n;
            float v = 0.f;
            if (kk < K && col < N) v = W[kk * N + col];
            Bs[k][n] = v;
        }
        __syncthreads();
        #pragma unroll
        for (int k = 0; k < KC; ++k) {
            float a[4], w[4];
            #pragma unroll
            for (int r = 0; r < 4; ++r) a[r] = As[k][ty * 4 + r];
            #pragma unroll
            for (int r = 0; r < 4; ++r) w[r] = Bs[k][tx * 4 + r];
            #pragma unroll
            for (int i = 0; i < 4; ++i)
                #pragma unroll
                for (int j = 0; j < 4; ++j)
                    acc[i][j] = fmaf(a[i], w[j], acc[i][j]);
        }
        __syncthreads();
    }
    #pragma unroll
    for (int i = 0; i < 4; ++i) {
        int row = row0 + ty * 4 + i;
        if (row >= M) continue;
        #pragma unroll
        for (int j = 0; j < 4; ++j) {
            int col = col0 + tx * 4 + j;
            if (col >= N) continue;
            float v = acc[i][j];
            if (bias) v += bias[col];
            if (ACT == 1) v = (v > 0.f) ? v : expm1f(v);
            C[row * ldc + coff + col] = v;
        }
    }
}

// ---------------- Fused attention ----------------
__global__ __launch_bounds__(256)
void attn_k(const float* __restrict__ h, const float* __restrict__ h1,
            const float* __restrict__ h2, const float* __restrict__ bvec,
            const float* __restrict__ cptr,
            const int* __restrict__ x1, const int* __restrict__ x2,
            float* __restrict__ s_fw, float* __restrict__ s_bw)
{
    const int blk = blockIdx.x;          // 0..2047
    const int i = blk & 127;             // query position
    const int base = blk & ~127;         // row of key 0 for this (seq,b)
    const int d = threadIdx.x;
    const int* ids = (blk < 1024) ? x1 : x2;
    const int loc_q = blk & 1023;
    const int loc_k0 = base & 1023;

    const float cval = cptr[0];
    const float LOG2E = 1.4426950408889634f;
    const float k1 = 2.0f * LOG2E / cval;
    const bool mask_i = (ids[loc_q] == PAD_ID);

    float p = 0.f;
    if (d < D) p = h1[blk * D + d] + bvec[d];

    float l_fw = 0.f, l_bw = 0.f, a_fw = 0.f, a_bw = 0.f, hsum = 0.f;

    for (int j = 0; j < 128; ++j) {
        const bool mask_j = (ids[loc_k0 + j] == PAD_ID);
        const bool pad = mask_i || mask_j;
        float h2j = 0.f, hj = 0.f;
        if (d < D) {
            h2j = h2[(base + j) * D + d];
            hj  = h[(base + j) * D + d];
        }
        float e2 = __builtin_amdgcn_exp2f((p + h2j) * k1);
        float traw = fmaf(-2.0f * cval, __builtin_amdgcn_rcpf(e2 + 1.0f), cval);
        float tfw = (pad || (j <= i)) ? NEG_INF : traw;
        float tbw = (pad || (i <= j)) ? NEG_INF : traw;
        float efw = __builtin_amdgcn_exp2f(tfw * LOG2E);
        float ebw = __builtin_amdgcn_exp2f(tbw * LOG2E);
        l_fw += efw; a_fw = fmaf(efw, hj, a_fw);
        l_bw += ebw; a_bw = fmaf(ebw, hj, a_bw);
        hsum += hj;
    }
    if (d < D) {
        float sf = (l_fw > 0.f) ? (a_fw / l_fw) : (hsum * (1.0f / 128.0f));
        float sb = (l_bw > 0.f) ? (a_bw / l_bw) : (hsum * (1.0f / 128.0f));
        s_fw[blk * D + d] = sf;
        s_bw[blk * D + d] = sb;
    }
}

// ---------------- Fusion gate + u assembly ----------------
__global__ __launch_bounds__(256)
void ucomb_k(const float* __restrict__ h, const float* __restrict__ hf2,
             const float* __restrict__ s_fw, const float* __restrict__ s_bw,
             float* __restrict__ u)
{
    int idx = blockIdx.x * 256 + threadIdx.x;
    if (idx >= NROWS * D) return;
    int row = idx / D, d = idx - row * D;
    float g_fw = u[row * 400 + d];
    float g_bw = u[row * 400 + 200 + d];
    float hv = h[idx], hf = hf2[idx];
    float sf = s_fw[idx], sb = s_bw[idx];
    float ffw = 1.0f / (1.0f + __expf(-(g_fw + hf)));
    float fbw = 1.0f / (1.0f + __expf(-(g_bw + hf)));
    u[row * 400 + d]       = ffw * hv + (1.f - ffw) * sf;
    u[row * 400 + 200 + d] = fbw * hv + (1.f - fbw) * sb;
}

// ---------------- Per-(seq,b) weighted sum over L (parallel) ----------------
// grid (16, 7); block 256 = 64 n-lanes x 4 l-groups of 32
__global__ __launch_bounds__(256)
void reduce_k(const float* __restrict__ u, const float* __restrict__ atts,
              float* __restrict__ bv)
{
    __shared__ float p[4][64];
    const int sb = blockIdx.x;       // 0..15
    const int nt = blockIdx.y;       // 0..6
    const int tid = threadIdx.x;
    const int nl = tid & 63, lg = tid >> 6;
    const int n = nt * 64 + nl;
    float acc = 0.f;
    if (n < 400) {
        const int r0 = sb * 128 + lg * 32;
        #pragma unroll 4
        for (int l = 0; l < 32; ++l)
            acc = fmaf(u[(r0 + l) * 400 + n], atts[(r0 + l) * 400 + n], acc);
    }
    p[lg][nl] = acc;
    __syncthreads();
    if (tid < 64 && n < 400)
        bv[sb * 400 + n] = p[0][nl] + p[1][nl] + p[2][nl] + p[3][nl];
}

// ---------------- Final MLP: k-split partial GEMM ----------------
// grid 32 blocks: seg = bid>>3 in {cv, rv, cv-rv, cv*rv}, kr0 = (bid&7)*50
#define KT 50
__global__ __launch_bounds__(256)
void final1_part_k(const float* __restrict__ bv, const float* __restrict__ F1w,
                   float* __restrict__ part)
{
    __shared__ float feats[8][KT];
    const int bid = blockIdx.x;      // 0..31
    const int seg = bid >> 3;
    const int kr0 = (bid & 7) * KT;
    const int tid = threadIdx.x;
    for (int idx = tid; idx < 8 * KT; idx += 256) {
        int b = idx / KT, kk = idx - b * KT;
        float cv = bv[b * 400 + kr0 + kk];
        float rv = bv[(8 + b) * 400 + kr0 + kk];
        feats[b][kk] = (seg == 0) ? cv : (seg == 1) ? rv
                     : (seg == 2) ? (cv - rv) : (cv * rv);
    }
    __syncthreads();
    const int n = tid;
    if (n >= 200) return;
    const int kbase = seg * 400 + kr0;
    float acc[8] = {};
    #pragma unroll 5
    for (int kk = 0; kk < KT; ++kk) {
        float w = F1w[(kbase + kk) * 200 + n];
        #pragma unroll
        for (int b = 0; b < 8; ++b)
            acc[b] = fmaf(feats[b][kk], w, acc[b]);
    }
    #pragma unroll
    for (int b = 0; b < 8; ++b)
        part[(bid * 8 + b) * 200 + n] = acc[b];
}

__global__ __launch_bounds__(256)
void final2_k(const float* __restrict__ part, const float* __restrict__ F1b,
              const float* __restrict__ F2w, const float* __restrict__ F2b,
              float* __restrict__ y)
{
    __shared__ float red[256];
    const int b = blockIdx.x, tid = threadIdx.x;
    float v = 0.f;
    if (tid < 200) {
        float s = F1b[tid];
        #pragma unroll 8
        for (int t = 0; t < 32; ++t)
            s += part[(t * 8 + b) * 200 + tid];
        v = fmaxf(s, 0.f) * F2w[tid];
    }
    red[tid] = v;
    __syncthreads();
    for (int off = 128; off; off >>= 1) {
        if (tid < off) red[tid] += red[tid + off];
        __syncthreads();
    }
    if (tid == 0) y[b] = red[0] + F2b[0];
}

extern "C" void kernel_launch(void* const* d_in, const int* in_sizes, int n_in,
                              void* d_out, int out_size, void* d_ws, size_t ws_size,
                              hipStream_t stream)
{
    const int*   x1    = (const int*)d_in[0];
    const int*   x2    = (const int*)d_in[1];
    const float* emb   = (const float*)d_in[2];
    const float* Wh_w  = (const float*)d_in[3];
    const float* Wh_b  = (const float*)d_in[4];
    const float* W1_w  = (const float*)d_in[5];
    const float* W2_w  = (const float*)d_in[6];
    const float* bvec  = (const float*)d_in[7];
    const float* cptr  = (const float*)d_in[8];
    const float* Wf1_w = (const float*)d_in[9];
    const float* Wf2_w = (const float*)d_in[10];
    const float* Wf2_b = (const float*)d_in[11];
    const float* Ws1_w = (const float*)d_in[12];
    const float* Ws1_b = (const float*)d_in[13];
    const float* Ws_w  = (const float*)d_in[14];
    const float* Ws_b  = (const float*)d_in[15];
    const float* F1_w  = (const float*)d_in[16];
    const float* F1_b  = (const float*)d_in[17];
    const float* F2_w  = (const float*)d_in[18];
    const float* F2_b  = (const float*)d_in[19];
    float* y = (float*)d_out;

    float* ws = (float*)d_ws;
    float* h    = ws;
    float* h1   = h    + NROWS * D;
    float* h2   = h1   + NROWS * D;
    float* hf2  = h2   + NROWS * D;
    float* sfw  = hf2  + NROWS * D;
    float* sbw  = sfw  + NROWS * D;
    float* u    = sbw  + NROWS * D;       // NROWS*400
    float* v1   = u    + NROWS * 400;
    float* atts = v1   + NROWS * 400;
    float* bv   = atts + NROWS * 400;     // 16*400
    float* part = bv   + 16 * 400;        // 32*8*200

    dim3 blk(256);
    dim3 g200((200 + TN - 1) / TN, NROWS / TM);   // 4 x 32
    dim3 g400((400 + TN - 1) / TN, NROWS / TM);   // 7 x 32

    gemm_k<1, 1><<<g200, blk, 0, stream>>>(nullptr, x1, x2, emb, Wh_w, Wh_b,
                                           h, NROWS, D, D, D, 0);
    gemm_k<0, 0><<<g200, blk, 0, stream>>>(h, nullptr, nullptr, nullptr, W1_w, nullptr,
                                           h1, NROWS, D, D, D, 0);
    gemm_k<0, 0><<<g200, blk, 0, stream>>>(h, nullptr, nullptr, nullptr, W2_w, nullptr,
                                           h2, NROWS, D, D, D, 0);
    gemm_k<0, 0><<<g200, blk, 0, stream>>>(h, nullptr, nullptr, nullptr, Wf2_w, Wf2_b,
                                           hf2, NROWS, D, D, D, 0);
    attn_k<<<dim3(NROWS), blk, 0, stream>>>(h, h1, h2, bvec, cptr, x1, x2, sfw, sbw);
    gemm_k<0, 0><<<g200, blk, 0, stream>>>(sfw, nullptr, nullptr, nullptr, Wf1_w, nullptr,
                                           u, NROWS, D, D, 400, 0);
    gemm_k<0, 0><<<g200, blk, 0, stream>>>(sbw, nullptr, nullptr, nullptr, Wf1_w, nullptr,
                                           u, NROWS, D, D, 400, 200);
    ucomb_k<<<dim3(NROWS * D / 256), blk, 0, stream>>>(h, hf2, sfw, sbw, u);
    gemm_k<1, 0><<<g400, blk, 0, stream>>>(u, nullptr, nullptr, nullptr, Ws1_w, Ws1_b,
                                           v1, NROWS, 400, 400, 400, 0);
    gemm_k<0, 0><<<g400, blk, 0, stream>>>(v1, nullptr, nullptr, nullptr, Ws_w, Ws_b,
                                           atts, NROWS, 400, 400, 400, 0);
    reduce_k<<<dim3(16, 7), blk, 0, stream>>>(u, atts, bv);
    final1_part_k<<<dim3(32), blk, 0, stream>>>(bv, F1_w, part);
    final2_k<<<dim3(8), blk, 0, stream>>>(part, F1_b, F2_w, F2_b, y);
}

// Round 3
// 188.149 us; speedup vs baseline: 3.2038x; 2.4715x over previous
//
#include <hip/hip_runtime.h>
#include <hip/hip_bf16.h>
#include <math.h>

// Problem constants
#define B 8
#define L 128
#define D 200
#define NROWS 2048          // 2 sequences * B * L
#define PAD_ID 1
#define NEG_INF (-1e13f)

// ---------------- Tiled f32 GEMM, TM=32 x TN=64, 2x4 micro, reg-prefetch ----------------
// thread grid 16tx x 16ty; thread computes rows ty*2..+1, cols tx*4..+3
// WMODE: 0 = plain W[k*N+col]; 1 = proj3 (W0|W1p|W2p each [k*200+...], bias only col>=400)
// EMODE: 0 = bias; 1 = bias+ELU; 2 = ucomb epilogue (Wf1 gate fusion)
// GATHER: A row r = emb[ids(r)]
template<int WMODE, int EMODE, int GATHER>
__global__ __launch_bounds__(256)
void gemm2_k(const float* __restrict__ A,
             const int* __restrict__ x1, const int* __restrict__ x2,
             const float* __restrict__ emb,
             const float* __restrict__ W0, const float* __restrict__ W1p,
             const float* __restrict__ W2p, const float* __restrict__ bias,
             const float* __restrict__ hbuf, const float* __restrict__ hPbuf,
             float* __restrict__ C, int M, int N, int K, int ldc)
{
    __shared__ float As[16][34];
    __shared__ float Bs[16][68];
    const int row0 = blockIdx.y * 32, col0 = blockIdx.x * 64;
    const int tid = threadIdx.x;
    const int tx = tid & 15, ty = tid >> 4;

    float ra[2], rb[4];
    const int nK = (K + 15) >> 4;

    // prefetch tile 0
    {
        const int kk = tid & 15;
        #pragma unroll
        for (int p = 0; p < 2; ++p) {
            int row = row0 + (tid >> 4) + p * 16;
            float v = 0.f;
            if (kk < K) {
                if (GATHER) { int id = (row < 1024) ? x1[row] : x2[row - 1024];
                              v = emb[id * K + kk]; }
                else v = A[row * K + kk];
            }
            ra[p] = v;
        }
        const int nn = col0 + (tid & 63);
        #pragma unroll
        for (int p = 0; p < 4; ++p) {
            int kk2 = (tid >> 6) + p * 4;
            float v = 0.f;
            if (kk2 < K && nn < N) {
                if (WMODE == 1)
                    v = (nn < 200) ? W0[kk2 * 200 + nn]
                      : (nn < 400) ? W1p[kk2 * 200 + nn - 200]
                                   : W2p[kk2 * 200 + nn - 400];
                else v = W0[kk2 * N + nn];
            }
            rb[p] = v;
        }
    }

    float acc[2][4] = {};
    for (int kc = 0; kc < nK; ++kc) {
        __syncthreads();
        As[tid & 15][tid >> 4]      = ra[0];
        As[tid & 15][(tid >> 4)+16] = ra[1];
        #pragma unroll
        for (int p = 0; p < 4; ++p) Bs[(tid >> 6) + p * 4][tid & 63] = rb[p];
        __syncthreads();

        if (kc + 1 < nK) {
            const int k0 = (kc + 1) * 16;
            const int kk = k0 + (tid & 15);
            #pragma unroll
            for (int p = 0; p < 2; ++p) {
                int row = row0 + (tid >> 4) + p * 16;
                float v = 0.f;
                if (kk < K) {
                    if (GATHER) { int id = (row < 1024) ? x1[row] : x2[row - 1024];
                                  v = emb[id * K + kk]; }
                    else v = A[row * K + kk];
                }
                ra[p] = v;
            }
            const int nn = col0 + (tid & 63);
            #pragma unroll
            for (int p = 0; p < 4; ++p) {
                int kk2 = k0 + (tid >> 6) + p * 4;
                float v = 0.f;
                if (kk2 < K && nn < N) {
                    if (WMODE == 1)
                        v = (nn < 200) ? W0[kk2 * 200 + nn]
                          : (nn < 400) ? W1p[kk2 * 200 + nn - 200]
                                       : W2p[kk2 * 200 + nn - 400];
                    else v = W0[kk2 * N + nn];
                }
                rb[p] = v;
            }
        }

        #pragma unroll
        for (int k = 0; k < 16; ++k) {
            float a0 = As[k][ty * 2], a1 = As[k][ty * 2 + 1];
            float w0 = Bs[k][tx * 4], w1 = Bs[k][tx * 4 + 1];
            float w2 = Bs[k][tx * 4 + 2], w3 = Bs[k][tx * 4 + 3];
            acc[0][0] = fmaf(a0, w0, acc[0][0]); acc[0][1] = fmaf(a0, w1, acc[0][1]);
            acc[0][2] = fmaf(a0, w2, acc[0][2]); acc[0][3] = fmaf(a0, w3, acc[0][3]);
            acc[1][0] = fmaf(a1, w0, acc[1][0]); acc[1][1] = fmaf(a1, w1, acc[1][1]);
            acc[1][2] = fmaf(a1, w2, acc[1][2]); acc[1][3] = fmaf(a1, w3, acc[1][3]);
        }
    }

    #pragma unroll
    for (int i = 0; i < 2; ++i) {
        const int row = row0 + ty * 2 + i;
        #pragma unroll
        for (int j = 0; j < 4; ++j) {
            const int col = col0 + tx * 4 + j;
            if (col >= N) continue;
            float v = acc[i][j];
            if (EMODE == 2) {
                // row in [0,4096): sr = row & 2047, half = row >> 11
                const int sr = row & 2047, half = row >> 11;
                float g = v + hPbuf[sr * 600 + 400 + col];      // + hf2
                float f = 1.0f / (1.0f + __expf(-g));
                float s = A[row * 200 + col];                    // sfw/sbw
                float hv = hbuf[sr * 200 + col];
                C[sr * 400 + half * 200 + col] = f * hv + (1.f - f) * s;
            } else {
                if (WMODE == 1) { if (bias && col >= 400) v += bias[col - 400]; }
                else if (bias) v += bias[col];
                if (EMODE == 1) v = (v > 0.f) ? v : expm1f(v);
                C[row * ldc + col] = v;
            }
        }
    }
}

// ---------------- Fused attention ----------------
// h stride 200; h1 = hP + 0, h2 = hP + 200, both stride 600
__global__ __launch_bounds__(256)
void attn_k(const float* __restrict__ h, const float* __restrict__ hP,
            const float* __restrict__ bvec, const float* __restrict__ cptr,
            const int* __restrict__ x1, const int* __restrict__ x2,
            float* __restrict__ s_fw, float* __restrict__ s_bw)
{
    const int blk = blockIdx.x;          // 0..2047
    const int i = blk & 127;
    const int base = blk & ~127;
    const int d = threadIdx.x;
    const int* ids = (blk < 1024) ? x1 : x2;
    const int loc_q = blk & 1023;
    const int loc_k0 = base & 1023;

    const float cval = cptr[0];
    const float LOG2E = 1.4426950408889634f;
    const float k1 = 2.0f * LOG2E / cval;
    const bool mask_i = (ids[loc_q] == PAD_ID);

    float p = 0.f;
    if (d < D) p = hP[blk * 600 + d] + bvec[d];

    float l_fw = 0.f, l_bw = 0.f, a_fw = 0.f, a_bw = 0.f, hsum = 0.f;

    for (int j = 0; j < 128; ++j) {
        const bool mask_j = (ids[loc_k0 + j] == PAD_ID);
        const bool pad = mask_i || mask_j;
        float h2j = 0.f, hj = 0.f;
        if (d < D) {
            h2j = hP[(base + j) * 600 + 200 + d];
            hj  = h[(base + j) * 200 + d];
        }
        float e2 = __builtin_amdgcn_exp2f((p + h2j) * k1);
        float traw = fmaf(-2.0f * cval, __builtin_amdgcn_rcpf(e2 + 1.0f), cval);
        float tfw = (pad || (j <= i)) ? NEG_INF : traw;
        float tbw = (pad || (i <= j)) ? NEG_INF : traw;
        float efw = __builtin_amdgcn_exp2f(tfw * LOG2E);
        float ebw = __builtin_amdgcn_exp2f(tbw * LOG2E);
        l_fw += efw; a_fw = fmaf(efw, hj, a_fw);
        l_bw += ebw; a_bw = fmaf(ebw, hj, a_bw);
        hsum += hj;
    }
    if (d < D) {
        float sf = (l_fw > 0.f) ? (a_fw / l_fw) : (hsum * (1.0f / 128.0f));
        float sb = (l_bw > 0.f) ? (a_bw / l_bw) : (hsum * (1.0f / 128.0f));
        s_fw[blk * D + d] = sf;
        s_bw[blk * D + d] = sb;
    }
}

// ---------------- Per-(seq,b) weighted sum over L ----------------
__global__ __launch_bounds__(256)
void reduce_k(const float* __restrict__ u, const float* __restrict__ atts,
              float* __restrict__ bv)
{
    __shared__ float p[4][64];
    const int sb = blockIdx.x, nt = blockIdx.y;
    const int tid = threadIdx.x;
    const int nl = tid & 63, lg = tid >> 6;
    const int n = nt * 64 + nl;
    float acc = 0.f;
    if (n < 400) {
        const int r0 = sb * 128 + lg * 32;
        #pragma unroll 4
        for (int l = 0; l < 32; ++l)
            acc = fmaf(u[(r0 + l) * 400 + n], atts[(r0 + l) * 400 + n], acc);
    }
    p[lg][nl] = acc;
    __syncthreads();
    if (tid < 64 && n < 400)
        bv[sb * 400 + n] = p[0][nl] + p[1][nl] + p[2][nl] + p[3][nl];
}

// ---------------- Final MLP ----------------
#define KT 50
__global__ __launch_bounds__(256)
void final1_part_k(const float* __restrict__ bv, const float* __restrict__ F1w,
                   float* __restrict__ part)
{
    __shared__ float feats[8][KT];
    const int bid = blockIdx.x;
    const int seg = bid >> 3;
    const int kr0 = (bid & 7) * KT;
    const int tid = threadIdx.x;
    for (int idx = tid; idx < 8 * KT; idx += 256) {
        int b = idx / KT, kk = idx - b * KT;
        float cv = bv[b * 400 + kr0 + kk];
        float rv = bv[(8 + b) * 400 + kr0 + kk];
        feats[b][kk] = (seg == 0) ? cv : (seg == 1) ? rv
                     : (seg == 2) ? (cv - rv) : (cv * rv);
    }
    __syncthreads();
    const int n = tid;
    if (n >= 200) return;
    const int kbase = seg * 400 + kr0;
    float acc[8] = {};
    #pragma unroll 5
    for (int kk = 0; kk < KT; ++kk) {
        float w = F1w[(kbase + kk) * 200 + n];
        #pragma unroll
        for (int b = 0; b < 8; ++b)
            acc[b] = fmaf(feats[b][kk], w, acc[b]);
    }
    #pragma unroll
    for (int b = 0; b < 8; ++b)
        part[(bid * 8 + b) * 200 + n] = acc[b];
}

__global__ __launch_bounds__(256)
void final2_k(const float* __restrict__ part, const float* __restrict__ F1b,
              const float* __restrict__ F2w, const float* __restrict__ F2b,
              float* __restrict__ y)
{
    __shared__ float red[256];
    const int b = blockIdx.x, tid = threadIdx.x;
    float v = 0.f;
    if (tid < 200) {
        float s = F1b[tid];
        #pragma unroll 8
        for (int t = 0; t < 32; ++t)
            s += part[(t * 8 + b) * 200 + tid];
        v = fmaxf(s, 0.f) * F2w[tid];
    }
    red[tid] = v;
    __syncthreads();
    for (int off = 128; off; off >>= 1) {
        if (tid < off) red[tid] += red[tid + off];
        __syncthreads();
    }
    if (tid == 0) y[b] = red[0] + F2b[0];
}

extern "C" void kernel_launch(void* const* d_in, const int* in_sizes, int n_in,
                              void* d_out, int out_size, void* d_ws, size_t ws_size,
                              hipStream_t stream)
{
    const int*   x1    = (const int*)d_in[0];
    const int*   x2    = (const int*)d_in[1];
    const float* emb   = (const float*)d_in[2];
    const float* Wh_w  = (const float*)d_in[3];
    const float* Wh_b  = (const float*)d_in[4];
    const float* W1_w  = (const float*)d_in[5];
    const float* W2_w  = (const float*)d_in[6];
    const float* bvec  = (const float*)d_in[7];
    const float* cptr  = (const float*)d_in[8];
    const float* Wf1_w = (const float*)d_in[9];
    const float* Wf2_w = (const float*)d_in[10];
    const float* Wf2_b = (const float*)d_in[11];
    const float* Ws1_w = (const float*)d_in[12];
    const float* Ws1_b = (const float*)d_in[13];
    const float* Ws_w  = (const float*)d_in[14];
    const float* Ws_b  = (const float*)d_in[15];
    const float* F1_w  = (const float*)d_in[16];
    const float* F1_b  = (const float*)d_in[17];
    const float* F2_w  = (const float*)d_in[18];
    const float* F2_b  = (const float*)d_in[19];
    float* y = (float*)d_out;

    float* ws = (float*)d_ws;
    float* h    = ws;                     // 2048*200
    float* hP   = h    + NROWS * D;       // 2048*600 (h1|h2|hf2)
    float* sfw  = hP   + NROWS * 600;     // 2048*200
    float* sbw  = sfw  + NROWS * D;       // 2048*200 (contiguous after sfw!)
    float* u    = sbw  + NROWS * D;       // 2048*400
    float* v1   = u    + NROWS * 400;
    float* atts = v1   + NROWS * 400;
    float* bv   = atts + NROWS * 400;     // 16*400
    float* part = bv   + 16 * 400;        // 32*8*200

    dim3 blk(256);

    // 1. h = elu(emb[x] @ Wh + Wh_b)            grid 4x64
    gemm2_k<0, 1, 1><<<dim3(4, 64), blk, 0, stream>>>(
        nullptr, x1, x2, emb, Wh_w, nullptr, nullptr, Wh_b,
        nullptr, nullptr, h, NROWS, 200, 200, 200);
    // 2. hP = h @ [W1|W2|Wf2] (+Wf2_b on last)  grid 10x64
    gemm2_k<1, 0, 0><<<dim3(10, 64), blk, 0, stream>>>(
        h, nullptr, nullptr, nullptr, W1_w, W2_w, Wf2_w, Wf2_b,
        nullptr, nullptr, hP, NROWS, 600, 200, 600);
    // 3. attention
    attn_k<<<dim3(NROWS), blk, 0, stream>>>(h, hP, bvec, cptr, x1, x2, sfw, sbw);
    // 4. u = gate(s @ Wf1) fused                grid 4x128 (M=4096)
    gemm2_k<0, 2, 0><<<dim3(4, 128), blk, 0, stream>>>(
        sfw, nullptr, nullptr, nullptr, Wf1_w, nullptr, nullptr, nullptr,
        h, hP, u, 2 * NROWS, 200, 200, 400);
    // 5. v1 = elu(u @ Ws1 + Ws1_b)              grid 7x64
    gemm2_k<0, 1, 0><<<dim3(7, 64), blk, 0, stream>>>(
        u, nullptr, nullptr, nullptr, Ws1_w, nullptr, nullptr, Ws1_b,
        nullptr, nullptr, v1, NROWS, 400, 400, 400);
    // 6. atts = v1 @ Ws + Ws_b                  grid 7x64
    gemm2_k<0, 0, 0><<<dim3(7, 64), blk, 0, stream>>>(
        v1, nullptr, nullptr, nullptr, Ws_w, nullptr, nullptr, Ws_b,
        nullptr, nullptr, atts, NROWS, 400, 400, 400);
    // 7. bv = sum_l u * atts
    reduce_k<<<dim3(16, 7), blk, 0, stream>>>(u, atts, bv);
    // 8-9. final MLP
    final1_part_k<<<dim3(32), blk, 0, stream>>>(bv, F1_w, part);
    final2_k<<<dim3(8), blk, 0, stream>>>(part, F1_b, F2_w, F2_b, y);
}

// Round 4
// 187.958 us; speedup vs baseline: 3.2071x; 1.0010x over previous
//
#include <hip/hip_runtime.h>
#include <hip/hip_bf16.h>
#include <math.h>

// Problem constants
#define B 8
#define L 128
#define D 200
#define NROWS 2048          // 2 sequences * B * L
#define PAD_ID 1
#define NEG_INF (-1e13f)

// ---------------- Tiled f32 GEMM, TM=32 x TN=64, 2x4 micro, reg-prefetch ----------------
template<int WMODE, int EMODE, int GATHER>
__global__ __launch_bounds__(256)
void gemm2_k(const float* __restrict__ A,
             const int* __restrict__ x1, const int* __restrict__ x2,
             const float* __restrict__ emb,
             const float* __restrict__ W0, const float* __restrict__ W1p,
             const float* __restrict__ W2p, const float* __restrict__ bias,
             const float* __restrict__ hbuf, const float* __restrict__ hPbuf,
             float* __restrict__ C, int M, int N, int K, int ldc)
{
    __shared__ float As[16][34];
    __shared__ float Bs[16][68];
    const int row0 = blockIdx.y * 32, col0 = blockIdx.x * 64;
    const int tid = threadIdx.x;
    const int tx = tid & 15, ty = tid >> 4;

    float ra[2], rb[4];
    const int nK = (K + 15) >> 4;

    {
        const int kk = tid & 15;
        #pragma unroll
        for (int p = 0; p < 2; ++p) {
            int row = row0 + (tid >> 4) + p * 16;
            float v = 0.f;
            if (kk < K) {
                if (GATHER) { int id = (row < 1024) ? x1[row] : x2[row - 1024];
                              v = emb[id * K + kk]; }
                else v = A[row * K + kk];
            }
            ra[p] = v;
        }
        const int nn = col0 + (tid & 63);
        #pragma unroll
        for (int p = 0; p < 4; ++p) {
            int kk2 = (tid >> 6) + p * 4;
            float v = 0.f;
            if (kk2 < K && nn < N) {
                if (WMODE == 1)
                    v = (nn < 200) ? W0[kk2 * 200 + nn]
                      : (nn < 400) ? W1p[kk2 * 200 + nn - 200]
                                   : W2p[kk2 * 200 + nn - 400];
                else v = W0[kk2 * N + nn];
            }
            rb[p] = v;
        }
    }

    float acc[2][4] = {};
    for (int kc = 0; kc < nK; ++kc) {
        __syncthreads();
        As[tid & 15][tid >> 4]      = ra[0];
        As[tid & 15][(tid >> 4)+16] = ra[1];
        #pragma unroll
        for (int p = 0; p < 4; ++p) Bs[(tid >> 6) + p * 4][tid & 63] = rb[p];
        __syncthreads();

        if (kc + 1 < nK) {
            const int k0 = (kc + 1) * 16;
            const int kk = k0 + (tid & 15);
            #pragma unroll
            for (int p = 0; p < 2; ++p) {
                int row = row0 + (tid >> 4) + p * 16;
                float v = 0.f;
                if (kk < K) {
                    if (GATHER) { int id = (row < 1024) ? x1[row] : x2[row - 1024];
                                  v = emb[id * K + kk]; }
                    else v = A[row * K + kk];
                }
                ra[p] = v;
            }
            const int nn = col0 + (tid & 63);
            #pragma unroll
            for (int p = 0; p < 4; ++p) {
                int kk2 = k0 + (tid >> 6) + p * 4;
                float v = 0.f;
                if (kk2 < K && nn < N) {
                    if (WMODE == 1)
                        v = (nn < 200) ? W0[kk2 * 200 + nn]
                          : (nn < 400) ? W1p[kk2 * 200 + nn - 200]
                                       : W2p[kk2 * 200 + nn - 400];
                    else v = W0[kk2 * N + nn];
                }
                rb[p] = v;
            }
        }

        #pragma unroll
        for (int k = 0; k < 16; ++k) {
            float a0 = As[k][ty * 2], a1 = As[k][ty * 2 + 1];
            float w0 = Bs[k][tx * 4], w1 = Bs[k][tx * 4 + 1];
            float w2 = Bs[k][tx * 4 + 2], w3 = Bs[k][tx * 4 + 3];
            acc[0][0] = fmaf(a0, w0, acc[0][0]); acc[0][1] = fmaf(a0, w1, acc[0][1]);
            acc[0][2] = fmaf(a0, w2, acc[0][2]); acc[0][3] = fmaf(a0, w3, acc[0][3]);
            acc[1][0] = fmaf(a1, w0, acc[1][0]); acc[1][1] = fmaf(a1, w1, acc[1][1]);
            acc[1][2] = fmaf(a1, w2, acc[1][2]); acc[1][3] = fmaf(a1, w3, acc[1][3]);
        }
    }

    #pragma unroll
    for (int i = 0; i < 2; ++i) {
        const int row = row0 + ty * 2 + i;
        #pragma unroll
        for (int j = 0; j < 4; ++j) {
            const int col = col0 + tx * 4 + j;
            if (col >= N) continue;
            float v = acc[i][j];
            if (EMODE == 2) {
                const int sr = row & 2047, half = row >> 11;
                float g = v + hPbuf[sr * 600 + 400 + col];      // + hf2
                float f = 1.0f / (1.0f + __expf(-g));
                float s = A[row * 200 + col];                    // sfw/sbw
                float hv = hbuf[sr * 200 + col];
                C[sr * 400 + half * 200 + col] = f * hv + (1.f - f) * s;
            } else {
                if (WMODE == 1) { if (bias && col >= 400) v += bias[col - 400]; }
                else if (bias) v += bias[col];
                if (EMODE == 1) v = (v > 0.f) ? v : expm1f(v);
                C[row * ldc + col] = v;
            }
        }
    }
}

// ---------------- Fused attention v2: QCHUNK=4, 3-phase loop, 3-trans scoring ----------
// w' = exp(t - c) = exp2(m / (exp2((p+h2)*k1) + 1)), m = -2c*log2e; e^c cancels in a/l.
__global__ __launch_bounds__(256)
void attn_k(const float* __restrict__ h, const float* __restrict__ hP,
            const float* __restrict__ bvec, const float* __restrict__ cptr,
            const int* __restrict__ x1, const int* __restrict__ x2,
            float* __restrict__ s_fw, float* __restrict__ s_bw)
{
    const int blk = blockIdx.x;      // 0..511
    const int sb  = blk >> 5;        // 0..15 (seq*batch)
    const int i0  = (blk & 31) * 4;  // first query row of this chunk
    const int base = sb * 128;       // global row of key 0
    const int d = threadIdx.x;
    const int* ids = (sb < 8) ? x1 : x2;
    const int loc0 = (sb & 7) * 128;

    const float cval = cptr[0];
    const float LOG2E = 1.4426950408889634f;
    const float k1 = 2.0f * LOG2E / cval;
    const float mcoef = -2.0f * cval * LOG2E;

    float pqk[4];
    bool mi[4];
    #pragma unroll
    for (int q = 0; q < 4; ++q) {
        mi[q] = (ids[loc0 + i0 + q] == PAD_ID);
        float v = 0.f;
        if (d < D) v = (hP[(base + i0 + q) * 600 + d] + bvec[d]) * k1;
        pqk[q] = v;
    }

    float lfw[4] = {}, afw[4] = {}, lbw[4] = {}, abw[4] = {};
    float hsum = 0.f;

    auto score = [&](int q, float h2k) -> float {
        float e2 = __builtin_amdgcn_exp2f(pqk[q] + h2k);
        return __builtin_amdgcn_exp2f(mcoef * __builtin_amdgcn_rcpf(e2 + 1.0f));
    };

    int j = 0;
    // Phase A: j < i0 — all queries take bw
    for (; j < i0; ++j) {
        float h2j = 0.f, hj = 0.f;
        if (d < D) {
            h2j = hP[(base + j) * 600 + 200 + d];
            hj  = h[(base + j) * 200 + d];
        }
        hsum += hj;
        if (ids[loc0 + j] != PAD_ID) {
            float h2k = h2j * k1;
            #pragma unroll
            for (int q = 0; q < 4; ++q) {
                float w = score(q, h2k);
                lbw[q] += w; abw[q] = fmaf(w, hj, abw[q]);
            }
        }
    }
    // Phase B: j in [i0, i0+4) — mixed
    for (; j < i0 + 4; ++j) {
        float h2j = 0.f, hj = 0.f;
        if (d < D) {
            h2j = hP[(base + j) * 600 + 200 + d];
            hj  = h[(base + j) * 200 + d];
        }
        hsum += hj;
        if (ids[loc0 + j] != PAD_ID) {
            float h2k = h2j * k1;
            #pragma unroll
            for (int q = 0; q < 4; ++q) {
                if (j == i0 + q) continue;
                float w = score(q, h2k);
                if (j > i0 + q) { lfw[q] += w; afw[q] = fmaf(w, hj, afw[q]); }
                else            { lbw[q] += w; abw[q] = fmaf(w, hj, abw[q]); }
            }
        }
    }
    // Phase C: j >= i0+4 — all queries take fw
    for (; j < 128; ++j) {
        float h2j = 0.f, hj = 0.f;
        if (d < D) {
            h2j = hP[(base + j) * 600 + 200 + d];
            hj  = h[(base + j) * 200 + d];
        }
        hsum += hj;
        if (ids[loc0 + j] != PAD_ID) {
            float h2k = h2j * k1;
            #pragma unroll
            for (int q = 0; q < 4; ++q) {
                float w = score(q, h2k);
                lfw[q] += w; afw[q] = fmaf(w, hj, afw[q]);
            }
        }
    }

    if (d < D) {
        const float fb = hsum * (1.0f / 128.0f);
        #pragma unroll
        for (int q = 0; q < 4; ++q) {
            float sf = (!mi[q] && lfw[q] > 0.f) ? (afw[q] / lfw[q]) : fb;
            float sb_ = (!mi[q] && lbw[q] > 0.f) ? (abw[q] / lbw[q]) : fb;
            s_fw[(base + i0 + q) * D + d] = sf;
            s_bw[(base + i0 + q) * D + d] = sb_;
        }
    }
}

// ---------------- Per-(seq,b) weighted sum over L ----------------
__global__ __launch_bounds__(256)
void reduce_k(const float* __restrict__ u, const float* __restrict__ atts,
              float* __restrict__ bv)
{
    __shared__ float p[4][64];
    const int sb = blockIdx.x, nt = blockIdx.y;
    const int tid = threadIdx.x;
    const int nl = tid & 63, lg = tid >> 6;
    const int n = nt * 64 + nl;
    float acc = 0.f;
    if (n < 400) {
        const int r0 = sb * 128 + lg * 32;
        #pragma unroll 4
        for (int l = 0; l < 32; ++l)
            acc = fmaf(u[(r0 + l) * 400 + n], atts[(r0 + l) * 400 + n], acc);
    }
    p[lg][nl] = acc;
    __syncthreads();
    if (tid < 64 && n < 400)
        bv[sb * 400 + n] = p[0][nl] + p[1][nl] + p[2][nl] + p[3][nl];
}

// ---------------- Final MLP ----------------
#define KT 50
__global__ __launch_bounds__(256)
void final1_part_k(const float* __restrict__ bv, const float* __restrict__ F1w,
                   float* __restrict__ part)
{
    __shared__ float feats[8][KT];
    const int bid = blockIdx.x;
    const int seg = bid >> 3;
    const int kr0 = (bid & 7) * KT;
    const int tid = threadIdx.x;
    for (int idx = tid; idx < 8 * KT; idx += 256) {
        int b = idx / KT, kk = idx - b * KT;
        float cv = bv[b * 400 + kr0 + kk];
        float rv = bv[(8 + b) * 400 + kr0 + kk];
        feats[b][kk] = (seg == 0) ? cv : (seg == 1) ? rv
                     : (seg == 2) ? (cv - rv) : (cv * rv);
    }
    __syncthreads();
    const int n = tid;
    if (n >= 200) return;
    const int kbase = seg * 400 + kr0;
    float acc[8] = {};
    #pragma unroll 5
    for (int kk = 0; kk < KT; ++kk) {
        float w = F1w[(kbase + kk) * 200 + n];
        #pragma unroll
        for (int b = 0; b < 8; ++b)
            acc[b] = fmaf(feats[b][kk], w, acc[b]);
    }
    #pragma unroll
    for (int b = 0; b < 8; ++b)
        part[(bid * 8 + b) * 200 + n] = acc[b];
}

__global__ __launch_bounds__(256)
void final2_k(const float* __restrict__ part, const float* __restrict__ F1b,
              const float* __restrict__ F2w, const float* __restrict__ F2b,
              float* __restrict__ y)
{
    __shared__ float red[256];
    const int b = blockIdx.x, tid = threadIdx.x;
    float v = 0.f;
    if (tid < 200) {
        float s = F1b[tid];
        #pragma unroll 8
        for (int t = 0; t < 32; ++t)
            s += part[(t * 8 + b) * 200 + tid];
        v = fmaxf(s, 0.f) * F2w[tid];
    }
    red[tid] = v;
    __syncthreads();
    for (int off = 128; off; off >>= 1) {
        if (tid < off) red[tid] += red[tid + off];
        __syncthreads();
    }
    if (tid == 0) y[b] = red[0] + F2b[0];
}

extern "C" void kernel_launch(void* const* d_in, const int* in_sizes, int n_in,
                              void* d_out, int out_size, void* d_ws, size_t ws_size,
                              hipStream_t stream)
{
    const int*   x1    = (const int*)d_in[0];
    const int*   x2    = (const int*)d_in[1];
    const float* emb   = (const float*)d_in[2];
    const float* Wh_w  = (const float*)d_in[3];
    const float* Wh_b  = (const float*)d_in[4];
    const float* W1_w  = (const float*)d_in[5];
    const float* W2_w  = (const float*)d_in[6];
    const float* bvec  = (const float*)d_in[7];
    const float* cptr  = (const float*)d_in[8];
    const float* Wf1_w = (const float*)d_in[9];
    const float* Wf2_w = (const float*)d_in[10];
    const float* Wf2_b = (const float*)d_in[11];
    const float* Ws1_w = (const float*)d_in[12];
    const float* Ws1_b = (const float*)d_in[13];
    const float* Ws_w  = (const float*)d_in[14];
    const float* Ws_b  = (const float*)d_in[15];
    const float* F1_w  = (const float*)d_in[16];
    const float* F1_b  = (const float*)d_in[17];
    const float* F2_w  = (const float*)d_in[18];
    const float* F2_b  = (const float*)d_in[19];
    float* y = (float*)d_out;

    float* ws = (float*)d_ws;
    float* h    = ws;                     // 2048*200
    float* hP   = h    + NROWS * D;       // 2048*600 (h1|h2|hf2)
    float* sfw  = hP   + NROWS * 600;     // 2048*200
    float* sbw  = sfw  + NROWS * D;       // 2048*200 (contiguous after sfw)
    float* u    = sbw  + NROWS * D;       // 2048*400
    float* v1   = u    + NROWS * 400;
    float* atts = v1   + NROWS * 400;
    float* bv   = atts + NROWS * 400;     // 16*400
    float* part = bv   + 16 * 400;        // 32*8*200

    dim3 blk(256);

    gemm2_k<0, 1, 1><<<dim3(4, 64), blk, 0, stream>>>(
        nullptr, x1, x2, emb, Wh_w, nullptr, nullptr, Wh_b,
        nullptr, nullptr, h, NROWS, 200, 200, 200);
    gemm2_k<1, 0, 0><<<dim3(10, 64), blk, 0, stream>>>(
        h, nullptr, nullptr, nullptr, W1_w, W2_w, Wf2_w, Wf2_b,
        nullptr, nullptr, hP, NROWS, 600, 200, 600);
    attn_k<<<dim3(512), blk, 0, stream>>>(h, hP, bvec, cptr, x1, x2, sfw, sbw);
    gemm2_k<0, 2, 0><<<dim3(4, 128), blk, 0, stream>>>(
        sfw, nullptr, nullptr, nullptr, Wf1_w, nullptr, nullptr, nullptr,
        h, hP, u, 2 * NROWS, 200, 200, 400);
    gemm2_k<0, 1, 0><<<dim3(7, 64), blk, 0, stream>>>(
        u, nullptr, nullptr, nullptr, Ws1_w, nullptr, nullptr, Ws1_b,
        nullptr, nullptr, v1, NROWS, 400, 400, 400);
    gemm2_k<0, 0, 0><<<dim3(7, 64), blk, 0, stream>>>(
        v1, nullptr, nullptr, nullptr, Ws_w, nullptr, nullptr, Ws_b,
        nullptr, nullptr, atts, NROWS, 400, 400, 400);
    reduce_k<<<dim3(16, 7), blk, 0, stream>>>(u, atts, bv);
    final1_part_k<<<dim3(32), blk, 0, stream>>>(bv, F1_w, part);
    final2_k<<<dim3(8), blk, 0, stream>>>(part, F1_b, F2_w, F2_b, y);
}

// Round 5
// 184.689 us; speedup vs baseline: 3.2639x; 1.0177x over previous
//
#include <hip/hip_runtime.h>
#include <hip/hip_bf16.h>
#include <math.h>

// Problem constants
#define B 8
#define L 128
#define D 200
#define NROWS 2048          // 2 sequences * B * L
#define PAD_ID 1
#define NEG_INF (-1e13f)

// ---------------- Tiled f32 GEMM, TM=32 x TN=64, 2x4 micro, reg-prefetch ----------------
template<int WMODE, int EMODE, int GATHER>
__global__ __launch_bounds__(256)
void gemm2_k(const float* __restrict__ A,
             const int* __restrict__ x1, const int* __restrict__ x2,
             const float* __restrict__ emb,
             const float* __restrict__ W0, const float* __restrict__ W1p,
             const float* __restrict__ W2p, const float* __restrict__ bias,
             const float* __restrict__ hbuf, const float* __restrict__ hPbuf,
             float* __restrict__ C, int M, int N, int K, int ldc)
{
    __shared__ float As[16][34];
    __shared__ float Bs[16][68];
    const int row0 = blockIdx.y * 32, col0 = blockIdx.x * 64;
    const int tid = threadIdx.x;
    const int tx = tid & 15, ty = tid >> 4;

    float ra[2], rb[4];
    const int nK = (K + 15) >> 4;

    {
        const int kk = tid & 15;
        #pragma unroll
        for (int p = 0; p < 2; ++p) {
            int row = row0 + (tid >> 4) + p * 16;
            float v = 0.f;
            if (kk < K) {
                if (GATHER) { int id = (row < 1024) ? x1[row] : x2[row - 1024];
                              v = emb[id * K + kk]; }
                else v = A[row * K + kk];
            }
            ra[p] = v;
        }
        const int nn = col0 + (tid & 63);
        #pragma unroll
        for (int p = 0; p < 4; ++p) {
            int kk2 = (tid >> 6) + p * 4;
            float v = 0.f;
            if (kk2 < K && nn < N) {
                if (WMODE == 1)
                    v = (nn < 200) ? W0[kk2 * 200 + nn]
                      : (nn < 400) ? W1p[kk2 * 200 + nn - 200]
                                   : W2p[kk2 * 200 + nn - 400];
                else v = W0[kk2 * N + nn];
            }
            rb[p] = v;
        }
    }

    float acc[2][4] = {};
    for (int kc = 0; kc < nK; ++kc) {
        __syncthreads();
        As[tid & 15][tid >> 4]      = ra[0];
        As[tid & 15][(tid >> 4)+16] = ra[1];
        #pragma unroll
        for (int p = 0; p < 4; ++p) Bs[(tid >> 6) + p * 4][tid & 63] = rb[p];
        __syncthreads();

        if (kc + 1 < nK) {
            const int k0 = (kc + 1) * 16;
            const int kk = k0 + (tid & 15);
            #pragma unroll
            for (int p = 0; p < 2; ++p) {
                int row = row0 + (tid >> 4) + p * 16;
                float v = 0.f;
                if (kk < K) {
                    if (GATHER) { int id = (row < 1024) ? x1[row] : x2[row - 1024];
                                  v = emb[id * K + kk]; }
                    else v = A[row * K + kk];
                }
                ra[p] = v;
            }
            const int nn = col0 + (tid & 63);
            #pragma unroll
            for (int p = 0; p < 4; ++p) {
                int kk2 = k0 + (tid >> 6) + p * 4;
                float v = 0.f;
                if (kk2 < K && nn < N) {
                    if (WMODE == 1)
                        v = (nn < 200) ? W0[kk2 * 200 + nn]
                          : (nn < 400) ? W1p[kk2 * 200 + nn - 200]
                                       : W2p[kk2 * 200 + nn - 400];
                    else v = W0[kk2 * N + nn];
                }
                rb[p] = v;
            }
        }

        #pragma unroll
        for (int k = 0; k < 16; ++k) {
            float a0 = As[k][ty * 2], a1 = As[k][ty * 2 + 1];
            float w0 = Bs[k][tx * 4], w1 = Bs[k][tx * 4 + 1];
            float w2 = Bs[k][tx * 4 + 2], w3 = Bs[k][tx * 4 + 3];
            acc[0][0] = fmaf(a0, w0, acc[0][0]); acc[0][1] = fmaf(a0, w1, acc[0][1]);
            acc[0][2] = fmaf(a0, w2, acc[0][2]); acc[0][3] = fmaf(a0, w3, acc[0][3]);
            acc[1][0] = fmaf(a1, w0, acc[1][0]); acc[1][1] = fmaf(a1, w1, acc[1][1]);
            acc[1][2] = fmaf(a1, w2, acc[1][2]); acc[1][3] = fmaf(a1, w3, acc[1][3]);
        }
    }

    #pragma unroll
    for (int i = 0; i < 2; ++i) {
        const int row = row0 + ty * 2 + i;
        #pragma unroll
        for (int j = 0; j < 4; ++j) {
            const int col = col0 + tx * 4 + j;
            if (col >= N) continue;
            float v = acc[i][j];
            if (EMODE == 2) {
                const int sr = row & 2047, half = row >> 11;
                float g = v + hPbuf[sr * 600 + 400 + col];      // + hf2
                float f = 1.0f / (1.0f + __expf(-g));
                float s = A[row * 200 + col];                    // sfw/sbw
                float hv = hbuf[sr * 200 + col];
                C[sr * 400 + half * 200 + col] = f * hv + (1.f - f) * s;
            } else {
                if (WMODE == 1) { if (bias && col >= 400) v += bias[col - 400]; }
                else if (bias) v += bias[col];
                if (EMODE == 1) v = (v > 0.f) ? v : expm1f(v);
                C[row * ldc + col] = v;
            }
        }
    }
}

// ---------------- Fused attention v3: QCHUNK=2, grid 1024, j-unroll x2 ----------------
// w' = exp(t - c) = exp2(mcoef / (exp2((p+h2)*k1) + 1)), mcoef = -2c*log2e.
// e^c scale cancels in a/l. Masked terms are skipped (their exp underflows to 0
// in the reference). All-masked rows -> uniform fallback hsum/128.
__global__ __launch_bounds__(256)
void attn_k(const float* __restrict__ h, const float* __restrict__ hP,
            const float* __restrict__ bvec, const float* __restrict__ cptr,
            const int* __restrict__ x1, const int* __restrict__ x2,
            float* __restrict__ s_fw, float* __restrict__ s_bw)
{
    const int blk = blockIdx.x;      // 0..1023
    const int sb  = blk >> 6;        // seq*batch 0..15
    const int i0  = (blk & 63) * 2;  // first query row (even)
    const int base = sb * 128;
    const int d = threadIdx.x;
    const int* ids = (sb < 8) ? x1 : x2;
    const int loc0 = (sb & 7) * 128;

    const float cval = cptr[0];
    const float LOG2E = 1.4426950408889634f;
    const float k1 = 2.0f * LOG2E / cval;
    const float mcoef = -2.0f * cval * LOG2E;

    const bool mi0 = (ids[loc0 + i0] == PAD_ID);
    const bool mi1 = (ids[loc0 + i0 + 1] == PAD_ID);
    float pq0 = 0.f, pq1 = 0.f;
    if (d < D) {
        pq0 = (hP[(base + i0) * 600 + d] + bvec[d]) * k1;
        pq1 = (hP[(base + i0 + 1) * 600 + d] + bvec[d]) * k1;
    }

    float lf0 = 0.f, af0 = 0.f, lb0 = 0.f, ab0 = 0.f;
    float lf1 = 0.f, af1 = 0.f, lb1 = 0.f, ab1 = 0.f;
    float hsum = 0.f;

    auto sc = [&](float pq, float h2k) -> float {
        float e2 = __builtin_amdgcn_exp2f(pq + h2k);
        return __builtin_amdgcn_exp2f(mcoef * __builtin_amdgcn_rcpf(e2 + 1.0f));
    };
    auto ldrow = [&](int j, float& h2k, float& hj) {
        h2k = 0.f; hj = 0.f;
        if (d < D) {
            h2k = hP[(base + j) * 600 + 200 + d] * k1;
            hj  = h[(base + j) * 200 + d];
        }
    };

    // Phase A: j in [0, i0) -- bw for both queries (i0 even -> trip count even)
    for (int j = 0; j + 1 < i0; j += 2) {
        float h2a, ha, h2b, hb;
        ldrow(j, h2a, ha); ldrow(j + 1, h2b, hb);
        hsum += ha + hb;
        const bool va = (ids[loc0 + j] != PAD_ID);
        const bool vb = (ids[loc0 + j + 1] != PAD_ID);
        if (va) {
            float w0 = sc(pq0, h2a), w1 = sc(pq1, h2a);
            lb0 += w0; ab0 = fmaf(w0, ha, ab0);
            lb1 += w1; ab1 = fmaf(w1, ha, ab1);
        }
        if (vb) {
            float w0 = sc(pq0, h2b), w1 = sc(pq1, h2b);
            lb0 += w0; ab0 = fmaf(w0, hb, ab0);
            lb1 += w1; ab1 = fmaf(w1, hb, ab1);
        }
    }
    // Phase B: j = i0 (bw for q1 only), j = i0+1 (fw for q0 only)
    {
        float h2a, ha, h2b, hb;
        ldrow(i0, h2a, ha); ldrow(i0 + 1, h2b, hb);
        hsum += ha + hb;
        if (ids[loc0 + i0] != PAD_ID) {
            float w1 = sc(pq1, h2a);
            lb1 += w1; ab1 = fmaf(w1, ha, ab1);
        }
        if (ids[loc0 + i0 + 1] != PAD_ID) {
            float w0 = sc(pq0, h2b);
            lf0 += w0; af0 = fmaf(w0, hb, af0);
        }
    }
    // Phase C: j in [i0+2, 128) -- fw for both queries (trip count even)
    for (int j = i0 + 2; j < 128; j += 2) {
        float h2a, ha, h2b, hb;
        ldrow(j, h2a, ha); ldrow(j + 1, h2b, hb);
        hsum += ha + hb;
        const bool va = (ids[loc0 + j] != PAD_ID);
        const bool vb = (ids[loc0 + j + 1] != PAD_ID);
        if (va) {
            float w0 = sc(pq0, h2a), w1 = sc(pq1, h2a);
            lf0 += w0; af0 = fmaf(w0, ha, af0);
            lf1 += w1; af1 = fmaf(w1, ha, af1);
        }
        if (vb) {
            float w0 = sc(pq0, h2b), w1 = sc(pq1, h2b);
            lf0 += w0; af0 = fmaf(w0, hb, af0);
            lf1 += w1; af1 = fmaf(w1, hb, af1);
        }
    }

    if (d < D) {
        const float fb = hsum * (1.0f / 128.0f);
        float sf0 = (!mi0 && lf0 > 0.f) ? (af0 / lf0) : fb;
        float sb0 = (!mi0 && lb0 > 0.f) ? (ab0 / lb0) : fb;
        float sf1 = (!mi1 && lf1 > 0.f) ? (af1 / lf1) : fb;
        float sb1 = (!mi1 && lb1 > 0.f) ? (ab1 / lb1) : fb;
        s_fw[(base + i0) * D + d]     = sf0;
        s_bw[(base + i0) * D + d]     = sb0;
        s_fw[(base + i0 + 1) * D + d] = sf1;
        s_bw[(base + i0 + 1) * D + d] = sb1;
    }
}

// ---------------- Per-(seq,b) weighted sum over L ----------------
__global__ __launch_bounds__(256)
void reduce_k(const float* __restrict__ u, const float* __restrict__ atts,
              float* __restrict__ bv)
{
    __shared__ float p[4][64];
    const int sb = blockIdx.x, nt = blockIdx.y;
    const int tid = threadIdx.x;
    const int nl = tid & 63, lg = tid >> 6;
    const int n = nt * 64 + nl;
    float acc = 0.f;
    if (n < 400) {
        const int r0 = sb * 128 + lg * 32;
        #pragma unroll 4
        for (int l = 0; l < 32; ++l)
            acc = fmaf(u[(r0 + l) * 400 + n], atts[(r0 + l) * 400 + n], acc);
    }
    p[lg][nl] = acc;
    __syncthreads();
    if (tid < 64 && n < 400)
        bv[sb * 400 + n] = p[0][nl] + p[1][nl] + p[2][nl] + p[3][nl];
}

// ---------------- Final MLP ----------------
#define KT 50
__global__ __launch_bounds__(256)
void final1_part_k(const float* __restrict__ bv, const float* __restrict__ F1w,
                   float* __restrict__ part)
{
    __shared__ float feats[8][KT];
    const int bid = blockIdx.x;
    const int seg = bid >> 3;
    const int kr0 = (bid & 7) * KT;
    const int tid = threadIdx.x;
    for (int idx = tid; idx < 8 * KT; idx += 256) {
        int b = idx / KT, kk = idx - b * KT;
        float cv = bv[b * 400 + kr0 + kk];
        float rv = bv[(8 + b) * 400 + kr0 + kk];
        feats[b][kk] = (seg == 0) ? cv : (seg == 1) ? rv
                     : (seg == 2) ? (cv - rv) : (cv * rv);
    }
    __syncthreads();
    const int n = tid;
    if (n >= 200) return;
    const int kbase = seg * 400 + kr0;
    float acc[8] = {};
    #pragma unroll 5
    for (int kk = 0; kk < KT; ++kk) {
        float w = F1w[(kbase + kk) * 200 + n];
        #pragma unroll
        for (int b = 0; b < 8; ++b)
            acc[b] = fmaf(feats[b][kk], w, acc[b]);
    }
    #pragma unroll
    for (int b = 0; b < 8; ++b)
        part[(bid * 8 + b) * 200 + n] = acc[b];
}

__global__ __launch_bounds__(256)
void final2_k(const float* __restrict__ part, const float* __restrict__ F1b,
              const float* __restrict__ F2w, const float* __restrict__ F2b,
              float* __restrict__ y)
{
    __shared__ float red[256];
    const int b = blockIdx.x, tid = threadIdx.x;
    float v = 0.f;
    if (tid < 200) {
        float s = F1b[tid];
        #pragma unroll 8
        for (int t = 0; t < 32; ++t)
            s += part[(t * 8 + b) * 200 + tid];
        v = fmaxf(s, 0.f) * F2w[tid];
    }
    red[tid] = v;
    __syncthreads();
    for (int off = 128; off; off >>= 1) {
        if (tid < off) red[tid] += red[tid + off];
        __syncthreads();
    }
    if (tid == 0) y[b] = red[0] + F2b[0];
}

extern "C" void kernel_launch(void* const* d_in, const int* in_sizes, int n_in,
                              void* d_out, int out_size, void* d_ws, size_t ws_size,
                              hipStream_t stream)
{
    const int*   x1    = (const int*)d_in[0];
    const int*   x2    = (const int*)d_in[1];
    const float* emb   = (const float*)d_in[2];
    const float* Wh_w  = (const float*)d_in[3];
    const float* Wh_b  = (const float*)d_in[4];
    const float* W1_w  = (const float*)d_in[5];
    const float* W2_w  = (const float*)d_in[6];
    const float* bvec  = (const float*)d_in[7];
    const float* cptr  = (const float*)d_in[8];
    const float* Wf1_w = (const float*)d_in[9];
    const float* Wf2_w = (const float*)d_in[10];
    const float* Wf2_b = (const float*)d_in[11];
    const float* Ws1_w = (const float*)d_in[12];
    const float* Ws1_b = (const float*)d_in[13];
    const float* Ws_w  = (const float*)d_in[14];
    const float* Ws_b  = (const float*)d_in[15];
    const float* F1_w  = (const float*)d_in[16];
    const float* F1_b  = (const float*)d_in[17];
    const float* F2_w  = (const float*)d_in[18];
    const float* F2_b  = (const float*)d_in[19];
    float* y = (float*)d_out;

    float* ws = (float*)d_ws;
    float* h    = ws;                     // 2048*200
    float* hP   = h    + NROWS * D;       // 2048*600 (h1|h2|hf2)
    float* sfw  = hP   + NROWS * 600;     // 2048*200
    float* sbw  = sfw  + NROWS * D;       // 2048*200 (contiguous after sfw)
    float* u    = sbw  + NROWS * D;       // 2048*400
    float* v1   = u    + NROWS * 400;
    float* atts = v1   + NROWS * 400;
    float* bv   = atts + NROWS * 400;     // 16*400
    float* part = bv   + 16 * 400;        // 32*8*200

    dim3 blk(256);

    gemm2_k<0, 1, 1><<<dim3(4, 64), blk, 0, stream>>>(
        nullptr, x1, x2, emb, Wh_w, nullptr, nullptr, Wh_b,
        nullptr, nullptr, h, NROWS, 200, 200, 200);
    gemm2_k<1, 0, 0><<<dim3(10, 64), blk, 0, stream>>>(
        h, nullptr, nullptr, nullptr, W1_w, W2_w, Wf2_w, Wf2_b,
        nullptr, nullptr, hP, NROWS, 600, 200, 600);
    attn_k<<<dim3(1024), blk, 0, stream>>>(h, hP, bvec, cptr, x1, x2, sfw, sbw);
    gemm2_k<0, 2, 0><<<dim3(4, 128), blk, 0, stream>>>(
        sfw, nullptr, nullptr, nullptr, Wf1_w, nullptr, nullptr, nullptr,
        h, hP, u, 2 * NROWS, 200, 200, 400);
    gemm2_k<0, 1, 0><<<dim3(7, 64), blk, 0, stream>>>(
        u, nullptr, nullptr, nullptr, Ws1_w, nullptr, nullptr, Ws1_b,
        nullptr, nullptr, v1, NROWS, 400, 400, 400);
    gemm2_k<0, 0, 0><<<dim3(7, 64), blk, 0, stream>>>(
        v1, nullptr, nullptr, nullptr, Ws_w, nullptr, nullptr, Ws_b,
        nullptr, nullptr, atts, NROWS, 400, 400, 400);
    reduce_k<<<dim3(16, 7), blk, 0, stream>>>(u, atts, bv);
    final1_part_k<<<dim3(32), blk, 0, stream>>>(bv, F1_w, part);
    final2_k<<<dim3(8), blk, 0, stream>>>(part, F1_b, F2_w, F2_b, y);
}

// Round 6
// 172.104 us; speedup vs baseline: 3.5025x; 1.0731x over previous
//
#include <hip/hip_runtime.h>
#include <hip/hip_bf16.h>
#include <math.h>

// Problem constants
#define B 8
#define L 128
#define D 200
#define NROWS 2048          // 2 sequences * B * L
#define PAD_ID 1
#define NEG_INF (-1e13f)

// ---------------- Tiled f32 GEMM, TM=32 x TN=64, 2x4 micro, reg-prefetch ----------------
template<int WMODE, int EMODE, int GATHER>
__global__ __launch_bounds__(256)
void gemm2_k(const float* __restrict__ A,
             const int* __restrict__ x1, const int* __restrict__ x2,
             const float* __restrict__ emb,
             const float* __restrict__ W0, const float* __restrict__ W1p,
             const float* __restrict__ W2p, const float* __restrict__ bias,
             const float* __restrict__ hbuf, const float* __restrict__ hPbuf,
             float* __restrict__ C, int M, int N, int K, int ldc)
{
    __shared__ float As[16][34];
    __shared__ float Bs[16][68];
    const int row0 = blockIdx.y * 32, col0 = blockIdx.x * 64;
    const int tid = threadIdx.x;
    const int tx = tid & 15, ty = tid >> 4;

    float ra[2], rb[4];
    const int nK = (K + 15) >> 4;

    {
        const int kk = tid & 15;
        #pragma unroll
        for (int p = 0; p < 2; ++p) {
            int row = row0 + (tid >> 4) + p * 16;
            float v = 0.f;
            if (kk < K) {
                if (GATHER) { int id = (row < 1024) ? x1[row] : x2[row - 1024];
                              v = emb[id * K + kk]; }
                else v = A[row * K + kk];
            }
            ra[p] = v;
        }
        const int nn = col0 + (tid & 63);
        #pragma unroll
        for (int p = 0; p < 4; ++p) {
            int kk2 = (tid >> 6) + p * 4;
            float v = 0.f;
            if (kk2 < K && nn < N) {
                if (WMODE == 1)
                    v = (nn < 200) ? W0[kk2 * 200 + nn]
                      : (nn < 400) ? W1p[kk2 * 200 + nn - 200]
                                   : W2p[kk2 * 200 + nn - 400];
                else v = W0[kk2 * N + nn];
            }
            rb[p] = v;
        }
    }

    float acc[2][4] = {};
    for (int kc = 0; kc < nK; ++kc) {
        __syncthreads();
        As[tid & 15][tid >> 4]      = ra[0];
        As[tid & 15][(tid >> 4)+16] = ra[1];
        #pragma unroll
        for (int p = 0; p < 4; ++p) Bs[(tid >> 6) + p * 4][tid & 63] = rb[p];
        __syncthreads();

        if (kc + 1 < nK) {
            const int k0 = (kc + 1) * 16;
            const int kk = k0 + (tid & 15);
            #pragma unroll
            for (int p = 0; p < 2; ++p) {
                int row = row0 + (tid >> 4) + p * 16;
                float v = 0.f;
                if (kk < K) {
                    if (GATHER) { int id = (row < 1024) ? x1[row] : x2[row - 1024];
                                  v = emb[id * K + kk]; }
                    else v = A[row * K + kk];
                }
                ra[p] = v;
            }
            const int nn = col0 + (tid & 63);
            #pragma unroll
            for (int p = 0; p < 4; ++p) {
                int kk2 = k0 + (tid >> 6) + p * 4;
                float v = 0.f;
                if (kk2 < K && nn < N) {
                    if (WMODE == 1)
                        v = (nn < 200) ? W0[kk2 * 200 + nn]
                          : (nn < 400) ? W1p[kk2 * 200 + nn - 200]
                                       : W2p[kk2 * 200 + nn - 400];
                    else v = W0[kk2 * N + nn];
                }
                rb[p] = v;
            }
        }

        #pragma unroll
        for (int k = 0; k < 16; ++k) {
            float a0 = As[k][ty * 2], a1 = As[k][ty * 2 + 1];
            float w0 = Bs[k][tx * 4], w1 = Bs[k][tx * 4 + 1];
            float w2 = Bs[k][tx * 4 + 2], w3 = Bs[k][tx * 4 + 3];
            acc[0][0] = fmaf(a0, w0, acc[0][0]); acc[0][1] = fmaf(a0, w1, acc[0][1]);
            acc[0][2] = fmaf(a0, w2, acc[0][2]); acc[0][3] = fmaf(a0, w3, acc[0][3]);
            acc[1][0] = fmaf(a1, w0, acc[1][0]); acc[1][1] = fmaf(a1, w1, acc[1][1]);
            acc[1][2] = fmaf(a1, w2, acc[1][2]); acc[1][3] = fmaf(a1, w3, acc[1][3]);
        }
    }

    #pragma unroll
    for (int i = 0; i < 2; ++i) {
        const int row = row0 + ty * 2 + i;
        #pragma unroll
        for (int j = 0; j < 4; ++j) {
            const int col = col0 + tx * 4 + j;
            if (col >= N) continue;
            float v = acc[i][j];
            if (EMODE == 2) {
                const int sr = row & 2047, half = row >> 11;
                float g = v + hPbuf[sr * 600 + 400 + col];      // + hf2
                float f = 1.0f / (1.0f + __expf(-g));
                float s = A[row * 200 + col];                    // sfw/sbw
                float hv = hbuf[sr * 200 + col];
                C[sr * 400 + half * 200 + col] = f * hv + (1.f - f) * s;
            } else {
                if (WMODE == 1) { if (bias && col >= 400) v += bias[col - 400]; }
                else if (bias) v += bias[col];
                if (EMODE == 1) v = (v > 0.f) ? v : expm1f(v);
                C[row * ldc + col] = v;
            }
        }
    }
}

// ---------------- Attention partial: 2 queries x 64 keys per block ----------------
// grid 2048 = sb(16) x qc(64) x jh(2).  Writes 8 partial accumulators + hsum half.
// w' = exp2(mcoef / (exp2((p+h2)*k1) + 1)), mcoef = -2c*log2e (e^c cancels in a/l).
__global__ __launch_bounds__(256)
void attn_part_k(const float* __restrict__ h, const float* __restrict__ hP,
                 const float* __restrict__ bvec, const float* __restrict__ cptr,
                 const int* __restrict__ x1, const int* __restrict__ x2,
                 float* __restrict__ part, float* __restrict__ hsumP)
{
    const int blk = blockIdx.x;          // 0..2047
    const int jh  = blk & 1;
    const int qc  = (blk >> 1) & 63;
    const int sb  = blk >> 7;            // 0..15
    const int i0  = qc * 2;
    const int base = sb * 128;
    const int j0 = jh * 64, j1 = j0 + 64;
    const int d = threadIdx.x;
    const int* ids = (sb < 8) ? x1 : x2;
    const int loc0 = (sb & 7) * 128;

    const float cval = cptr[0];
    const float LOG2E = 1.4426950408889634f;
    const float k1 = 2.0f * LOG2E / cval;
    const float mcoef = -2.0f * cval * LOG2E;

    // key-pad bitmask over this block's 64 keys (one coalesced load + ballot)
    const int lane = threadIdx.x & 63;
    const unsigned long long km = __ballot(ids[loc0 + j0 + lane] == PAD_ID);

    float pq0 = 0.f, pq1 = 0.f;
    if (d < D) {
        pq0 = (hP[(base + i0) * 600 + d] + bvec[d]) * k1;
        pq1 = (hP[(base + i0 + 1) * 600 + d] + bvec[d]) * k1;
    }

    float lf0 = 0.f, af0 = 0.f, lb0 = 0.f, ab0 = 0.f;
    float lf1 = 0.f, af1 = 0.f, lb1 = 0.f, ab1 = 0.f;
    float hsum = 0.f;

    auto sc = [&](float pq, float h2k) -> float {
        float e2 = __builtin_amdgcn_exp2f(pq + h2k);
        return __builtin_amdgcn_exp2f(mcoef * __builtin_amdgcn_rcpf(e2 + 1.0f));
    };
    auto ldrow = [&](int j, float& h2k, float& hj) {
        h2k = 0.f; hj = 0.f;
        if (d < D) {
            h2k = hP[(base + j) * 600 + 200 + d] * k1;
            hj  = h[(base + j) * 200 + d];
        }
    };

    // Phase A: j in [j0, min(i0,j1)) -- bw for both queries (even trip count)
    const int aEnd = (i0 < j1) ? i0 : j1;
    for (int j = j0; j < aEnd; j += 2) {
        float h2a, ha, h2b, hb;
        ldrow(j, h2a, ha); ldrow(j + 1, h2b, hb);
        hsum += ha + hb;
        if (!((km >> (j - j0)) & 1ull)) {
            float w0 = sc(pq0, h2a), w1 = sc(pq1, h2a);
            lb0 += w0; ab0 = fmaf(w0, ha, ab0);
            lb1 += w1; ab1 = fmaf(w1, ha, ab1);
        }
        if (!((km >> (j + 1 - j0)) & 1ull)) {
            float w0 = sc(pq0, h2b), w1 = sc(pq1, h2b);
            lb0 += w0; ab0 = fmaf(w0, hb, ab0);
            lb1 += w1; ab1 = fmaf(w1, hb, ab1);
        }
    }
    // Phase B: rows i0 (bw for q1), i0+1 (fw for q0) -- both in same half when present
    if (i0 >= j0 && i0 < j1) {
        float h2a, ha, h2b, hb;
        ldrow(i0, h2a, ha); ldrow(i0 + 1, h2b, hb);
        hsum += ha + hb;
        if (!((km >> (i0 - j0)) & 1ull)) {
            float w1 = sc(pq1, h2a);
            lb1 += w1; ab1 = fmaf(w1, ha, ab1);
        }
        if (!((km >> (i0 + 1 - j0)) & 1ull)) {
            float w0 = sc(pq0, h2b);
            lf0 += w0; af0 = fmaf(w0, hb, af0);
        }
    }
    // Phase C: j in [max(i0+2,j0), j1) -- fw for both (even trip count)
    const int cs = (i0 + 2 > j0) ? i0 + 2 : j0;
    for (int j = cs; j < j1; j += 2) {
        float h2a, ha, h2b, hb;
        ldrow(j, h2a, ha); ldrow(j + 1, h2b, hb);
        hsum += ha + hb;
        if (!((km >> (j - j0)) & 1ull)) {
            float w0 = sc(pq0, h2a), w1 = sc(pq1, h2a);
            lf0 += w0; af0 = fmaf(w0, ha, af0);
            lf1 += w1; af1 = fmaf(w1, ha, af1);
        }
        if (!((km >> (j + 1 - j0)) & 1ull)) {
            float w0 = sc(pq0, h2b), w1 = sc(pq1, h2b);
            lf0 += w0; af0 = fmaf(w0, hb, af0);
            lf1 += w1; af1 = fmaf(w1, hb, af1);
        }
    }

    if (d < D) {
        float* pp = part + (size_t)blk * 1600;   // [blk][8][200]
        pp[0 * 200 + d] = lf0; pp[1 * 200 + d] = af0;
        pp[2 * 200 + d] = lb0; pp[3 * 200 + d] = ab0;
        pp[4 * 200 + d] = lf1; pp[5 * 200 + d] = af1;
        pp[6 * 200 + d] = lb1; pp[7 * 200 + d] = ab1;
        hsumP[(jh * 16 + sb) * 200 + d] = hsum;  // redundant across qc (same value)
    }
}

// ---------------- Attention combine: merge 2 j-halves, divide, fallback ----------------
__global__ __launch_bounds__(256)
void attn_comb_k(const float* __restrict__ part, const float* __restrict__ hsumP,
                 const int* __restrict__ x1, const int* __restrict__ x2,
                 float* __restrict__ s_fw, float* __restrict__ s_bw)
{
    const int g = blockIdx.x;            // 0..1023 = sb*64 + qc
    const int sb = g >> 6, qc = g & 63;
    const int i0 = qc * 2, base = sb * 128;
    const int d = threadIdx.x;
    if (d >= D) return;
    const int* ids = (sb < 8) ? x1 : x2;
    const int loc0 = (sb & 7) * 128;
    const bool mi0 = (ids[loc0 + i0] == PAD_ID);
    const bool mi1 = (ids[loc0 + i0 + 1] == PAD_ID);
    const float* p0 = part + (size_t)(sb * 128 + qc * 2 + 0) * 1600;
    const float* p1 = part + (size_t)(sb * 128 + qc * 2 + 1) * 1600;
    const float hsum = hsumP[(0 * 16 + sb) * 200 + d] + hsumP[(1 * 16 + sb) * 200 + d];
    const float fb = hsum * (1.0f / 128.0f);
    float lf0 = p0[0*200+d] + p1[0*200+d], af0 = p0[1*200+d] + p1[1*200+d];
    float lb0 = p0[2*200+d] + p1[2*200+d], ab0 = p0[3*200+d] + p1[3*200+d];
    float lf1 = p0[4*200+d] + p1[4*200+d], af1 = p0[5*200+d] + p1[5*200+d];
    float lb1 = p0[6*200+d] + p1[6*200+d], ab1 = p0[7*200+d] + p1[7*200+d];
    s_fw[(base + i0) * 200 + d]     = (!mi0 && lf0 > 0.f) ? af0 / lf0 : fb;
    s_bw[(base + i0) * 200 + d]     = (!mi0 && lb0 > 0.f) ? ab0 / lb0 : fb;
    s_fw[(base + i0 + 1) * 200 + d] = (!mi1 && lf1 > 0.f) ? af1 / lf1 : fb;
    s_bw[(base + i0 + 1) * 200 + d] = (!mi1 && lb1 > 0.f) ? ab1 / lb1 : fb;
}

// ---------------- Fallback monolithic attention (round-5 version) ----------------
__global__ __launch_bounds__(256)
void attn_k(const float* __restrict__ h, const float* __restrict__ hP,
            const float* __restrict__ bvec, const float* __restrict__ cptr,
            const int* __restrict__ x1, const int* __restrict__ x2,
            float* __restrict__ s_fw, float* __restrict__ s_bw)
{
    const int blk = blockIdx.x;      // 0..1023
    const int sb  = blk >> 6;
    const int i0  = (blk & 63) * 2;
    const int base = sb * 128;
    const int d = threadIdx.x;
    const int* ids = (sb < 8) ? x1 : x2;
    const int loc0 = (sb & 7) * 128;

    const float cval = cptr[0];
    const float LOG2E = 1.4426950408889634f;
    const float k1 = 2.0f * LOG2E / cval;
    const float mcoef = -2.0f * cval * LOG2E;

    const bool mi0 = (ids[loc0 + i0] == PAD_ID);
    const bool mi1 = (ids[loc0 + i0 + 1] == PAD_ID);
    float pq0 = 0.f, pq1 = 0.f;
    if (d < D) {
        pq0 = (hP[(base + i0) * 600 + d] + bvec[d]) * k1;
        pq1 = (hP[(base + i0 + 1) * 600 + d] + bvec[d]) * k1;
    }

    float lf0 = 0.f, af0 = 0.f, lb0 = 0.f, ab0 = 0.f;
    float lf1 = 0.f, af1 = 0.f, lb1 = 0.f, ab1 = 0.f;
    float hsum = 0.f;

    auto sc = [&](float pq, float h2k) -> float {
        float e2 = __builtin_amdgcn_exp2f(pq + h2k);
        return __builtin_amdgcn_exp2f(mcoef * __builtin_amdgcn_rcpf(e2 + 1.0f));
    };
    auto ldrow = [&](int j, float& h2k, float& hj) {
        h2k = 0.f; hj = 0.f;
        if (d < D) {
            h2k = hP[(base + j) * 600 + 200 + d] * k1;
            hj  = h[(base + j) * 200 + d];
        }
    };

    for (int j = 0; j + 1 < i0; j += 2) {
        float h2a, ha, h2b, hb;
        ldrow(j, h2a, ha); ldrow(j + 1, h2b, hb);
        hsum += ha + hb;
        if (ids[loc0 + j] != PAD_ID) {
            float w0 = sc(pq0, h2a), w1 = sc(pq1, h2a);
            lb0 += w0; ab0 = fmaf(w0, ha, ab0);
            lb1 += w1; ab1 = fmaf(w1, ha, ab1);
        }
        if (ids[loc0 + j + 1] != PAD_ID) {
            float w0 = sc(pq0, h2b), w1 = sc(pq1, h2b);
            lb0 += w0; ab0 = fmaf(w0, hb, ab0);
            lb1 += w1; ab1 = fmaf(w1, hb, ab1);
        }
    }
    {
        float h2a, ha, h2b, hb;
        ldrow(i0, h2a, ha); ldrow(i0 + 1, h2b, hb);
        hsum += ha + hb;
        if (ids[loc0 + i0] != PAD_ID) {
            float w1 = sc(pq1, h2a);
            lb1 += w1; ab1 = fmaf(w1, ha, ab1);
        }
        if (ids[loc0 + i0 + 1] != PAD_ID) {
            float w0 = sc(pq0, h2b);
            lf0 += w0; af0 = fmaf(w0, hb, af0);
        }
    }
    for (int j = i0 + 2; j < 128; j += 2) {
        float h2a, ha, h2b, hb;
        ldrow(j, h2a, ha); ldrow(j + 1, h2b, hb);
        hsum += ha + hb;
        if (ids[loc0 + j] != PAD_ID) {
            float w0 = sc(pq0, h2a), w1 = sc(pq1, h2a);
            lf0 += w0; af0 = fmaf(w0, ha, af0);
            lf1 += w1; af1 = fmaf(w1, ha, af1);
        }
        if (ids[loc0 + j + 1] != PAD_ID) {
            float w0 = sc(pq0, h2b), w1 = sc(pq1, h2b);
            lf0 += w0; af0 = fmaf(w0, hb, af0);
            lf1 += w1; af1 = fmaf(w1, hb, af1);
        }
    }

    if (d < D) {
        const float fb = hsum * (1.0f / 128.0f);
        s_fw[(base + i0) * D + d]     = (!mi0 && lf0 > 0.f) ? (af0 / lf0) : fb;
        s_bw[(base + i0) * D + d]     = (!mi0 && lb0 > 0.f) ? (ab0 / lb0) : fb;
        s_fw[(base + i0 + 1) * D + d] = (!mi1 && lf1 > 0.f) ? (af1 / lf1) : fb;
        s_bw[(base + i0 + 1) * D + d] = (!mi1 && lb1 > 0.f) ? (ab1 / lb1) : fb;
    }
}

// ---------------- Per-(seq,b) weighted sum over L ----------------
__global__ __launch_bounds__(256)
void reduce_k(const float* __restrict__ u, const float* __restrict__ atts,
              float* __restrict__ bv)
{
    __shared__ float p[4][64];
    const int sb = blockIdx.x, nt = blockIdx.y;
    const int tid = threadIdx.x;
    const int nl = tid & 63, lg = tid >> 6;
    const int n = nt * 64 + nl;
    float acc = 0.f;
    if (n < 400) {
        const int r0 = sb * 128 + lg * 32;
        #pragma unroll 4
        for (int l = 0; l < 32; ++l)
            acc = fmaf(u[(r0 + l) * 400 + n], atts[(r0 + l) * 400 + n], acc);
    }
    p[lg][nl] = acc;
    __syncthreads();
    if (tid < 64 && n < 400)
        bv[sb * 400 + n] = p[0][nl] + p[1][nl] + p[2][nl] + p[3][nl];
}

// ---------------- Final MLP ----------------
#define KT 50
__global__ __launch_bounds__(256)
void final1_part_k(const float* __restrict__ bv, const float* __restrict__ F1w,
                   float* __restrict__ part)
{
    __shared__ float feats[8][KT];
    const int bid = blockIdx.x;
    const int seg = bid >> 3;
    const int kr0 = (bid & 7) * KT;
    const int tid = threadIdx.x;
    for (int idx = tid; idx < 8 * KT; idx += 256) {
        int b = idx / KT, kk = idx - b * KT;
        float cv = bv[b * 400 + kr0 + kk];
        float rv = bv[(8 + b) * 400 + kr0 + kk];
        feats[b][kk] = (seg == 0) ? cv : (seg == 1) ? rv
                     : (seg == 2) ? (cv - rv) : (cv * rv);
    }
    __syncthreads();
    const int n = tid;
    if (n >= 200) return;
    const int kbase = seg * 400 + kr0;
    float acc[8] = {};
    #pragma unroll 5
    for (int kk = 0; kk < KT; ++kk) {
        float w = F1w[(kbase + kk) * 200 + n];
        #pragma unroll
        for (int b = 0; b < 8; ++b)
            acc[b] = fmaf(feats[b][kk], w, acc[b]);
    }
    #pragma unroll
    for (int b = 0; b < 8; ++b)
        part[(bid * 8 + b) * 200 + n] = acc[b];
}

__global__ __launch_bounds__(256)
void final2_k(const float* __restrict__ part, const float* __restrict__ F1b,
              const float* __restrict__ F2w, const float* __restrict__ F2b,
              float* __restrict__ y)
{
    __shared__ float red[256];
    const int b = blockIdx.x, tid = threadIdx.x;
    float v = 0.f;
    if (tid < 200) {
        float s = F1b[tid];
        #pragma unroll 8
        for (int t = 0; t < 32; ++t)
            s += part[(t * 8 + b) * 200 + tid];
        v = fmaxf(s, 0.f) * F2w[tid];
    }
    red[tid] = v;
    __syncthreads();
    for (int off = 128; off; off >>= 1) {
        if (tid < off) red[tid] += red[tid + off];
        __syncthreads();
    }
    if (tid == 0) y[b] = red[0] + F2b[0];
}

extern "C" void kernel_launch(void* const* d_in, const int* in_sizes, int n_in,
                              void* d_out, int out_size, void* d_ws, size_t ws_size,
                              hipStream_t stream)
{
    const int*   x1    = (const int*)d_in[0];
    const int*   x2    = (const int*)d_in[1];
    const float* emb   = (const float*)d_in[2];
    const float* Wh_w  = (const float*)d_in[3];
    const float* Wh_b  = (const float*)d_in[4];
    const float* W1_w  = (const float*)d_in[5];
    const float* W2_w  = (const float*)d_in[6];
    const float* bvec  = (const float*)d_in[7];
    const float* cptr  = (const float*)d_in[8];
    const float* Wf1_w = (const float*)d_in[9];
    const float* Wf2_w = (const float*)d_in[10];
    const float* Wf2_b = (const float*)d_in[11];
    const float* Ws1_w = (const float*)d_in[12];
    const float* Ws1_b = (const float*)d_in[13];
    const float* Ws_w  = (const float*)d_in[14];
    const float* Ws_b  = (const float*)d_in[15];
    const float* F1_w  = (const float*)d_in[16];
    const float* F1_b  = (const float*)d_in[17];
    const float* F2_w  = (const float*)d_in[18];
    const float* F2_b  = (const float*)d_in[19];
    float* y = (float*)d_out;

    float* ws = (float*)d_ws;
    float* h     = ws;                     // 409600
    float* hP    = h    + 409600;          // 1228800 (h1|h2|hf2, stride 600)
    float* sfw   = hP   + 1228800;         // 409600
    float* sbw   = sfw  + 409600;          // 409600 (contiguous after sfw)
    float* u     = sbw  + 409600;          // 819200
    float* v1    = u    + 819200;          // 819200
    float* atts  = v1   + 819200;          // 819200
    float* bv    = atts + 819200;          // 6400
    float* partM = bv   + 6400;            // 51200 (final MLP partials)
    // attention partials alias the (dead-at-that-point) u/v1/atts/... region
    float* attnP = u;                      // 2048*1600 = 3,276,800
    float* hsumP = attnP + 3276800;        // 6400
    const size_t need_bytes = (size_t)(2457600 + 3276800 + 6400) * 4; // 22,963,200

    dim3 blk(256);

    gemm2_k<0, 1, 1><<<dim3(4, 64), blk, 0, stream>>>(
        nullptr, x1, x2, emb, Wh_w, nullptr, nullptr, Wh_b,
        nullptr, nullptr, h, NROWS, 200, 200, 200);
    gemm2_k<1, 0, 0><<<dim3(10, 64), blk, 0, stream>>>(
        h, nullptr, nullptr, nullptr, W1_w, W2_w, Wf2_w, Wf2_b,
        nullptr, nullptr, hP, NROWS, 600, 200, 600);
    if (ws_size >= need_bytes) {
        attn_part_k<<<dim3(2048), blk, 0, stream>>>(h, hP, bvec, cptr, x1, x2,
                                                    attnP, hsumP);
        attn_comb_k<<<dim3(1024), blk, 0, stream>>>(attnP, hsumP, x1, x2, sfw, sbw);
    } else {
        attn_k<<<dim3(1024), blk, 0, stream>>>(h, hP, bvec, cptr, x1, x2, sfw, sbw);
    }
    gemm2_k<0, 2, 0><<<dim3(4, 128), blk, 0, stream>>>(
        sfw, nullptr, nullptr, nullptr, Wf1_w, nullptr, nullptr, nullptr,
        h, hP, u, 2 * NROWS, 200, 200, 400);
    gemm2_k<0, 1, 0><<<dim3(7, 64), blk, 0, stream>>>(
        u, nullptr, nullptr, nullptr, Ws1_w, nullptr, nullptr, Ws1_b,
        nullptr, nullptr, v1, NROWS, 400, 400, 400);
    gemm2_k<0, 0, 0><<<dim3(7, 64), blk, 0, stream>>>(
        v1, nullptr, nullptr, nullptr, Ws_w, nullptr, nullptr, Ws_b,
        nullptr, nullptr, atts, NROWS, 400, 400, 400);
    reduce_k<<<dim3(16, 7), blk, 0, stream>>>(u, atts, bv);
    final1_part_k<<<dim3(32), blk, 0, stream>>>(bv, F1_w, partM);
    final2_k<<<dim3(8), blk, 0, stream>>>(partM, F1_b, F2_w, F2_b, y);
}

// Round 7
// 163.995 us; speedup vs baseline: 3.6757x; 1.0494x over previous
//
#include <hip/hip_runtime.h>
#include <hip/hip_bf16.h>
#include <math.h>

// Problem constants
#define B 8
#define L 128
#define D 200
#define NROWS 2048          // 2 sequences * B * L
#define PAD_ID 1
#define LOG2E 1.4426950408889634f

// ---------------- Tiled f32 GEMM, TM=32 x TN=64, 2x4 micro, reg-prefetch ------------
// WMODE: 0 = plain W[k*ldw+col]; 1 = proj3 (W0|W1p|W2p each stride 200)
// EMODE: 0 = (+bias); 1 = bias+ELU; 2 = ucomb gate epilogue; 3 = proj3 precompute
//        (col<200 -> (v+bvec[col])*k1 ; col<400 -> v*k1 ; col>=400 -> v+Wf2_b)
// GATHER: A row r = emb[ids(r)]
// blockIdx.z = k-split slice: koff = z*K, C += z*M*ldc
template<int WMODE, int EMODE, int GATHER>
__global__ __launch_bounds__(256)
void gemm2_k(const float* __restrict__ A,
             const int* __restrict__ x1, const int* __restrict__ x2,
             const float* __restrict__ emb,
             const float* __restrict__ W0, const float* __restrict__ W1p,
             const float* __restrict__ W2p, const float* __restrict__ bias,
             const float* __restrict__ aux1, const float* __restrict__ aux2,
             float* __restrict__ C, int M, int N, int K,
             int lda, int ldw, int ldc)
{
    __shared__ float As[16][34];
    __shared__ float Bs[16][68];
    const int koff = blockIdx.z * K;
    A += koff;
    if (WMODE == 0) W0 += (size_t)koff * ldw;
    C += (size_t)blockIdx.z * M * ldc;

    const int row0 = blockIdx.y * 32, col0 = blockIdx.x * 64;
    const int tid = threadIdx.x;
    const int tx = tid & 15, ty = tid >> 4;

    float ra[2], rb[4];
    const int nK = (K + 15) >> 4;

    {
        const int kk = tid & 15;
        #pragma unroll
        for (int p = 0; p < 2; ++p) {
            int row = row0 + (tid >> 4) + p * 16;
            float v = 0.f;
            if (kk < K) {
                if (GATHER) { int id = (row < 1024) ? x1[row] : x2[row - 1024];
                              v = emb[id * lda + kk]; }
                else v = A[row * lda + kk];
            }
            ra[p] = v;
        }
        const int nn = col0 + (tid & 63);
        #pragma unroll
        for (int p = 0; p < 4; ++p) {
            int kk2 = (tid >> 6) + p * 4;
            float v = 0.f;
            if (kk2 < K && nn < N) {
                if (WMODE == 1)
                    v = (nn < 200) ? W0[kk2 * 200 + nn]
                      : (nn < 400) ? W1p[kk2 * 200 + nn - 200]
                                   : W2p[kk2 * 200 + nn - 400];
                else v = W0[kk2 * ldw + nn];
            }
            rb[p] = v;
        }
    }

    float acc[2][4] = {};
    for (int kc = 0; kc < nK; ++kc) {
        __syncthreads();
        As[tid & 15][tid >> 4]      = ra[0];
        As[tid & 15][(tid >> 4)+16] = ra[1];
        #pragma unroll
        for (int p = 0; p < 4; ++p) Bs[(tid >> 6) + p * 4][tid & 63] = rb[p];
        __syncthreads();

        if (kc + 1 < nK) {
            const int k0 = (kc + 1) * 16;
            const int kk = k0 + (tid & 15);
            #pragma unroll
            for (int p = 0; p < 2; ++p) {
                int row = row0 + (tid >> 4) + p * 16;
                float v = 0.f;
                if (kk < K) {
                    if (GATHER) { int id = (row < 1024) ? x1[row] : x2[row - 1024];
                                  v = emb[id * lda + kk]; }
                    else v = A[row * lda + kk];
                }
                ra[p] = v;
            }
            const int nn = col0 + (tid & 63);
            #pragma unroll
            for (int p = 0; p < 4; ++p) {
                int kk2 = k0 + (tid >> 6) + p * 4;
                float v = 0.f;
                if (kk2 < K && nn < N) {
                    if (WMODE == 1)
                        v = (nn < 200) ? W0[kk2 * 200 + nn]
                          : (nn < 400) ? W1p[kk2 * 200 + nn - 200]
                                       : W2p[kk2 * 200 + nn - 400];
                    else v = W0[kk2 * ldw + nn];
                }
                rb[p] = v;
            }
        }

        #pragma unroll
        for (int k = 0; k < 16; ++k) {
            float a0 = As[k][ty * 2], a1 = As[k][ty * 2 + 1];
            float w0 = Bs[k][tx * 4], w1 = Bs[k][tx * 4 + 1];
            float w2 = Bs[k][tx * 4 + 2], w3 = Bs[k][tx * 4 + 3];
            acc[0][0] = fmaf(a0, w0, acc[0][0]); acc[0][1] = fmaf(a0, w1, acc[0][1]);
            acc[0][2] = fmaf(a0, w2, acc[0][2]); acc[0][3] = fmaf(a0, w3, acc[0][3]);
            acc[1][0] = fmaf(a1, w0, acc[1][0]); acc[1][1] = fmaf(a1, w1, acc[1][1]);
            acc[1][2] = fmaf(a1, w2, acc[1][2]); acc[1][3] = fmaf(a1, w3, acc[1][3]);
        }
    }

    #pragma unroll
    for (int i = 0; i < 2; ++i) {
        const int row = row0 + ty * 2 + i;
        #pragma unroll
        for (int j = 0; j < 4; ++j) {
            const int col = col0 + tx * 4 + j;
            if (col >= N) continue;
            float v = acc[i][j];
            if (EMODE == 2) {
                const int sr = row & 2047, half = row >> 11;
                float g = v + aux2[sr * 600 + 400 + col];       // + hf2
                float f = 1.0f / (1.0f + __expf(-g));
                float s = A[row * lda + col];                    // sfw/sbw
                float hv = aux1[sr * 200 + col];
                C[sr * 400 + half * 200 + col] = f * hv + (1.f - f) * s;
            } else if (EMODE == 3) {
                const float k1 = 2.0f * LOG2E / aux2[0];
                if (col < 200)      v = (v + aux1[col]) * k1;
                else if (col < 400) v = v * k1;
                else                v += bias[col - 400];
                C[row * ldc + col] = v;
            } else {
                if (bias) v += bias[col];
                if (EMODE == 1) v = (v > 0.f) ? v : expm1f(v);
                C[row * ldc + col] = v;
            }
        }
    }
}

// ---------------- Attention partial: 4 queries x 32 keys per block ----------------
// hP h1-slot holds (h1+b)*k1, h2-slot holds h2*k1 (precomputed by proj3 EMODE3).
// w' = exp2(mcoef * rcp(exp2(pq+h2k)+1)), mcoef = -2c*log2e (e^c cancels in a/l).
__global__ __launch_bounds__(256)
void attn_part4_k(const float* __restrict__ h, const float* __restrict__ hP,
                  const float* __restrict__ cptr,
                  const int* __restrict__ x1, const int* __restrict__ x2,
                  float* __restrict__ part, float* __restrict__ hsumP)
{
    const int blk = blockIdx.x;          // 0..2047
    const int jq  = blk & 3;
    const int qc  = (blk >> 2) & 31;
    const int sb  = blk >> 7;            // 0..15
    const int i0  = qc * 4;
    const int base = sb * 128;
    const int j0 = jq * 32, j1 = j0 + 32;
    const int d = threadIdx.x;
    const int* ids = (sb < 8) ? x1 : x2;
    const int loc0 = (sb & 7) * 128;

    const float cval = cptr[0];
    const float mcoef = -2.0f * cval * LOG2E;

    // pad bitmask over this block's 32 keys (bits 0..31 valid)
    const unsigned long long km =
        __ballot(ids[loc0 + j0 + (threadIdx.x & 31)] == PAD_ID);

    float pq[4];
    #pragma unroll
    for (int q = 0; q < 4; ++q)
        pq[q] = (d < D) ? hP[(base + i0 + q) * 600 + d] : 0.f;

    float lf[4] = {}, af[4] = {}, lb[4] = {}, ab[4] = {};
    float hsum = 0.f;

    auto sc = [&](float p, float h2k) -> float {
        float e2 = __builtin_amdgcn_exp2f(p + h2k);
        return __builtin_amdgcn_exp2f(mcoef * __builtin_amdgcn_rcpf(e2 + 1.0f));
    };
    auto ldrow = [&](int j, float& h2k, float& hj) {
        h2k = 0.f; hj = 0.f;
        if (d < D) {
            h2k = hP[(base + j) * 600 + 200 + d];
            hj  = h[(base + j) * 200 + d];
        }
    };

    // Phase A: keys < i0 -> bw for all 4 queries (pair-unrolled; trip mult of 4)
    const int aEnd = (i0 < j1) ? i0 : j1;
    for (int j = j0; j < aEnd; j += 2) {
        float h2a, ha, h2b, hb;
        ldrow(j, h2a, ha); ldrow(j + 1, h2b, hb);
        hsum += ha + hb;
        if (!((km >> (j - j0)) & 1ull)) {
            #pragma unroll
            for (int q = 0; q < 4; ++q) {
                float w = sc(pq[q], h2a);
                lb[q] += w; ab[q] = fmaf(w, ha, ab[q]);
            }
        }
        if (!((km >> (j + 1 - j0)) & 1ull)) {
            #pragma unroll
            for (int q = 0; q < 4; ++q) {
                float w = sc(pq[q], h2b);
                lb[q] += w; ab[q] = fmaf(w, hb, ab[q]);
            }
        }
    }
    // Phase B: keys i0..i0+3 (mixed), entirely inside one 32-key window
    if (i0 >= j0 && i0 < j1) {
        #pragma unroll
        for (int jj = 0; jj < 4; ++jj) {
            const int j = i0 + jj;
            float h2a, ha;
            ldrow(j, h2a, ha);
            hsum += ha;
            if (!((km >> (j - j0)) & 1ull)) {
                #pragma unroll
                for (int q = 0; q < 4; ++q) {
                    if (jj == q) continue;
                    float w = sc(pq[q], h2a);
                    if (jj > q) { lf[q] += w; af[q] = fmaf(w, ha, af[q]); }
                    else        { lb[q] += w; ab[q] = fmaf(w, ha, ab[q]); }
                }
            }
        }
    }
    // Phase C: keys >= i0+4 -> fw for all 4 queries
    const int cs = (i0 + 4 > j0) ? i0 + 4 : j0;
    for (int j = cs; j < j1; j += 2) {
        float h2a, ha, h2b, hb;
        ldrow(j, h2a, ha); ldrow(j + 1, h2b, hb);
        hsum += ha + hb;
        if (!((km >> (j - j0)) & 1ull)) {
            #pragma unroll
            for (int q = 0; q < 4; ++q) {
                float w = sc(pq[q], h2a);
                lf[q] += w; af[q] = fmaf(w, ha, af[q]);
            }
        }
        if (!((km >> (j + 1 - j0)) & 1ull)) {
            #pragma unroll
            for (int q = 0; q < 4; ++q) {
                float w = sc(pq[q], h2b);
                lf[q] += w; af[q] = fmaf(w, hb, af[q]);
            }
        }
    }

    if (d < D) {
        float* pp = part + (size_t)blk * 3200;   // [blk][16][200]
        #pragma unroll
        for (int q = 0; q < 4; ++q) {
            pp[(q * 4 + 0) * 200 + d] = lf[q];
            pp[(q * 4 + 1) * 200 + d] = af[q];
            pp[(q * 4 + 2) * 200 + d] = lb[q];
            pp[(q * 4 + 3) * 200 + d] = ab[q];
        }
        hsumP[(jq * 16 + sb) * 200 + d] = hsum;  // same value across qc: deterministic
    }
}

// ---------------- Attention combine: merge 4 key-quarters, divide, fallback ---------
__global__ __launch_bounds__(256)
void attn_comb4_k(const float* __restrict__ part, const float* __restrict__ hsumP,
                  const int* __restrict__ x1, const int* __restrict__ x2,
                  float* __restrict__ s_fw, float* __restrict__ s_bw)
{
    const int g = blockIdx.x;            // 0..511 = sb*32 + qc
    const int sb = g >> 5, qc = g & 31;
    const int i0 = qc * 4, base = sb * 128;
    const int d = threadIdx.x;
    if (d >= D) return;
    const int* ids = (sb < 8) ? x1 : x2;
    const int loc0 = (sb & 7) * 128;
    float hs = 0.f;
    #pragma unroll
    for (int jq = 0; jq < 4; ++jq) hs += hsumP[(jq * 16 + sb) * 200 + d];
    const float fb = hs * (1.0f / 128.0f);
    #pragma unroll
    for (int q = 0; q < 4; ++q) {
        const bool mi = (ids[loc0 + i0 + q] == PAD_ID);
        float lf = 0.f, af = 0.f, lb = 0.f, ab = 0.f;
        #pragma unroll
        for (int jq = 0; jq < 4; ++jq) {
            const float* pp = part + ((size_t)(sb * 128 + qc * 4 + jq)) * 3200
                                   + (q * 4) * 200;
            lf += pp[d]; af += pp[200 + d]; lb += pp[400 + d]; ab += pp[600 + d];
        }
        s_fw[(base + i0 + q) * 200 + d] = (!mi && lf > 0.f) ? af / lf : fb;
        s_bw[(base + i0 + q) * 200 + d] = (!mi && lb > 0.f) ? ab / lb : fb;
    }
}

// ---------------- Fallback monolithic attention (pre-scaled hP) ----------------
__global__ __launch_bounds__(256)
void attn_k(const float* __restrict__ h, const float* __restrict__ hP,
            const float* __restrict__ cptr,
            const int* __restrict__ x1, const int* __restrict__ x2,
            float* __restrict__ s_fw, float* __restrict__ s_bw)
{
    const int blk = blockIdx.x;      // 0..1023
    const int sb  = blk >> 6;
    const int i0  = (blk & 63) * 2;
    const int base = sb * 128;
    const int d = threadIdx.x;
    const int* ids = (sb < 8) ? x1 : x2;
    const int loc0 = (sb & 7) * 128;

    const float cval = cptr[0];
    const float mcoef = -2.0f * cval * LOG2E;

    const bool mi0 = (ids[loc0 + i0] == PAD_ID);
    const bool mi1 = (ids[loc0 + i0 + 1] == PAD_ID);
    float pq0 = 0.f, pq1 = 0.f;
    if (d < D) {
        pq0 = hP[(base + i0) * 600 + d];
        pq1 = hP[(base + i0 + 1) * 600 + d];
    }

    float lf0 = 0.f, af0 = 0.f, lb0 = 0.f, ab0 = 0.f;
    float lf1 = 0.f, af1 = 0.f, lb1 = 0.f, ab1 = 0.f;
    float hsum = 0.f;

    auto sc = [&](float pq, float h2k) -> float {
        float e2 = __builtin_amdgcn_exp2f(pq + h2k);
        return __builtin_amdgcn_exp2f(mcoef * __builtin_amdgcn_rcpf(e2 + 1.0f));
    };
    auto ldrow = [&](int j, float& h2k, float& hj) {
        h2k = 0.f; hj = 0.f;
        if (d < D) {
            h2k = hP[(base + j) * 600 + 200 + d];
            hj  = h[(base + j) * 200 + d];
        }
    };

    for (int j = 0; j + 1 < i0; j += 2) {
        float h2a, ha, h2b, hb;
        ldrow(j, h2a, ha); ldrow(j + 1, h2b, hb);
        hsum += ha + hb;
        if (ids[loc0 + j] != PAD_ID) {
            float w0 = sc(pq0, h2a), w1 = sc(pq1, h2a);
            lb0 += w0; ab0 = fmaf(w0, ha, ab0);
            lb1 += w1; ab1 = fmaf(w1, ha, ab1);
        }
        if (ids[loc0 + j + 1] != PAD_ID) {
            float w0 = sc(pq0, h2b), w1 = sc(pq1, h2b);
            lb0 += w0; ab0 = fmaf(w0, hb, ab0);
            lb1 += w1; ab1 = fmaf(w1, hb, ab1);
        }
    }
    {
        float h2a, ha, h2b, hb;
        ldrow(i0, h2a, ha); ldrow(i0 + 1, h2b, hb);
        hsum += ha + hb;
        if (ids[loc0 + i0] != PAD_ID) {
            float w1 = sc(pq1, h2a);
            lb1 += w1; ab1 = fmaf(w1, ha, ab1);
        }
        if (ids[loc0 + i0 + 1] != PAD_ID) {
            float w0 = sc(pq0, h2b);
            lf0 += w0; af0 = fmaf(w0, hb, af0);
        }
    }
    for (int j = i0 + 2; j < 128; j += 2) {
        float h2a, ha, h2b, hb;
        ldrow(j, h2a, ha); ldrow(j + 1, h2b, hb);
        hsum += ha + hb;
        if (ids[loc0 + j] != PAD_ID) {
            float w0 = sc(pq0, h2a), w1 = sc(pq1, h2a);
            lf0 += w0; af0 = fmaf(w0, ha, af0);
            lf1 += w1; af1 = fmaf(w1, ha, af1);
        }
        if (ids[loc0 + j + 1] != PAD_ID) {
            float w0 = sc(pq0, h2b), w1 = sc(pq1, h2b);
            lf0 += w0; af0 = fmaf(w0, hb, af0);
            lf1 += w1; af1 = fmaf(w1, hb, af1);
        }
    }

    if (d < D) {
        const float fb = hsum * (1.0f / 128.0f);
        s_fw[(base + i0) * D + d]     = (!mi0 && lf0 > 0.f) ? (af0 / lf0) : fb;
        s_bw[(base + i0) * D + d]     = (!mi0 && lb0 > 0.f) ? (ab0 / lb0) : fb;
        s_fw[(base + i0 + 1) * D + d] = (!mi1 && lf1 > 0.f) ? (af1 / lf1) : fb;
        s_bw[(base + i0 + 1) * D + d] = (!mi1 && lb1 > 0.f) ? (ab1 / lb1) : fb;
    }
}

// ---------------- v1 = elu(sum of 4 k-split parts + bias) ----------------
__global__ __launch_bounds__(256)
void v1comb_k(const float* __restrict__ P, const float* __restrict__ bias,
              float* __restrict__ v1)
{
    const int idx = blockIdx.x * 256 + threadIdx.x;
    if (idx >= NROWS * 400) return;
    const int col = idx % 400;
    float s = P[idx] + P[idx + 819200] + P[idx + 2 * 819200] + P[idx + 3 * 819200]
            + bias[col];
    v1[idx] = (s > 0.f) ? s : expm1f(s);
}

// ---------------- bv = sum_l u * (sum of 4 Ws parts + Ws_b) ----------------
// grid (16, 7); block 256 = 64 cols x 4 row-groups of 32
__global__ __launch_bounds__(256)
void bvcomb_k(const float* __restrict__ u, const float* __restrict__ P,
              const float* __restrict__ bias, float* __restrict__ bv)
{
    __shared__ float red[4][64];
    const int sb = blockIdx.x, nt = blockIdx.y;
    const int tid = threadIdx.x;
    const int nl = tid & 63, lg = tid >> 6;
    const int n = nt * 64 + nl;
    float acc = 0.f;
    if (n < 400) {
        const float bn = bias[n];
        const int r0 = sb * 128 + lg * 32;
        for (int l = 0; l < 32; ++l) {
            const int idx = (r0 + l) * 400 + n;
            float a = P[idx] + P[idx + 819200] + P[idx + 2 * 819200]
                    + P[idx + 3 * 819200] + bn;
            acc = fmaf(u[idx], a, acc);
        }
    }
    red[lg][nl] = acc;
    __syncthreads();
    if (tid < 64 && n < 400)
        bv[sb * 400 + n] = red[0][nl] + red[1][nl] + red[2][nl] + red[3][nl];
}

// ---------------- Fallback reduce (when ws too small) ----------------
__global__ __launch_bounds__(256)
void reduce_k(const float* __restrict__ u, const float* __restrict__ atts,
              float* __restrict__ bv)
{
    __shared__ float p[4][64];
    const int sb = blockIdx.x, nt = blockIdx.y;
    const int tid = threadIdx.x;
    const int nl = tid & 63, lg = tid >> 6;
    const int n = nt * 64 + nl;
    float acc = 0.f;
    if (n < 400) {
        const int r0 = sb * 128 + lg * 32;
        #pragma unroll 4
        for (int l = 0; l < 32; ++l)
            acc = fmaf(u[(r0 + l) * 400 + n], atts[(r0 + l) * 400 + n], acc);
    }
    p[lg][nl] = acc;
    __syncthreads();
    if (tid < 64 && n < 400)
        bv[sb * 400 + n] = p[0][nl] + p[1][nl] + p[2][nl] + p[3][nl];
}

// ---------------- Final MLP ----------------
#define KT 50
__global__ __launch_bounds__(256)
void final1_part_k(const float* __restrict__ bv, const float* __restrict__ F1w,
                   float* __restrict__ part)
{
    __shared__ float feats[8][KT];
    const int bid = blockIdx.x;
    const int seg = bid >> 3;
    const int kr0 = (bid & 7) * KT;
    const int tid = threadIdx.x;
    for (int idx = tid; idx < 8 * KT; idx += 256) {
        int b = idx / KT, kk = idx - b * KT;
        float cv = bv[b * 400 + kr0 + kk];
        float rv = bv[(8 + b) * 400 + kr0 + kk];
        feats[b][kk] = (seg == 0) ? cv : (seg == 1) ? rv
                     : (seg == 2) ? (cv - rv) : (cv * rv);
    }
    __syncthreads();
    const int n = tid;
    if (n >= 200) return;
    const int kbase = seg * 400 + kr0;
    float acc[8] = {};
    #pragma unroll 5
    for (int kk = 0; kk < KT; ++kk) {
        float w = F1w[(kbase + kk) * 200 + n];
        #pragma unroll
        for (int b = 0; b < 8; ++b)
            acc[b] = fmaf(feats[b][kk], w, acc[b]);
    }
    #pragma unroll
    for (int b = 0; b < 8; ++b)
        part[(bid * 8 + b) * 200 + n] = acc[b];
}

__global__ __launch_bounds__(256)
void final2_k(const float* __restrict__ part, const float* __restrict__ F1b,
              const float* __restrict__ F2w, const float* __restrict__ F2b,
              float* __restrict__ y)
{
    __shared__ float red[256];
    const int b = blockIdx.x, tid = threadIdx.x;
    float v = 0.f;
    if (tid < 200) {
        float s = F1b[tid];
        #pragma unroll 8
        for (int t = 0; t < 32; ++t)
            s += part[(t * 8 + b) * 200 + tid];
        v = fmaxf(s, 0.f) * F2w[tid];
    }
    red[tid] = v;
    __syncthreads();
    for (int off = 128; off; off >>= 1) {
        if (tid < off) red[tid] += red[tid + off];
        __syncthreads();
    }
    if (tid == 0) y[b] = red[0] + F2b[0];
}

extern "C" void kernel_launch(void* const* d_in, const int* in_sizes, int n_in,
                              void* d_out, int out_size, void* d_ws, size_t ws_size,
                              hipStream_t stream)
{
    const int*   x1    = (const int*)d_in[0];
    const int*   x2    = (const int*)d_in[1];
    const float* emb   = (const float*)d_in[2];
    const float* Wh_w  = (const float*)d_in[3];
    const float* Wh_b  = (const float*)d_in[4];
    const float* W1_w  = (const float*)d_in[5];
    const float* W2_w  = (const float*)d_in[6];
    const float* bvec  = (const float*)d_in[7];
    const float* cptr  = (const float*)d_in[8];
    const float* Wf1_w = (const float*)d_in[9];
    const float* Wf2_w = (const float*)d_in[10];
    const float* Wf2_b = (const float*)d_in[11];
    const float* Ws1_w = (const float*)d_in[12];
    const float* Ws1_b = (const float*)d_in[13];
    const float* Ws_w  = (const float*)d_in[14];
    const float* Ws_b  = (const float*)d_in[15];
    const float* F1_w  = (const float*)d_in[16];
    const float* F1_b  = (const float*)d_in[17];
    const float* F2_w  = (const float*)d_in[18];
    const float* F2_b  = (const float*)d_in[19];
    float* y = (float*)d_out;

    float* ws = (float*)d_ws;
    float* h     = ws;                    // 409600
    float* hP    = h     + 409600;        // 1228800 ((h1+b)*k1 | h2*k1 | hf2)
    float* sfw   = hP    + 1228800;       // 409600
    float* sbw   = sfw   + 409600;        // 409600 (contiguous after sfw)
    float* u     = sbw   + 409600;        // 819200
    float* v1    = u     + 819200;        // 819200
    float* bv    = v1    + 819200;        // 6400
    float* partM = bv    + 6400;          // 51200
    float* hsumP = partM + 51200;         // 12800
    float* P     = hsumP + 12800;         // 6553600 (attnP -> ws1P -> wsP, sequential)
    const size_t need_bytes = (size_t)(10720000) * 4;   // 42.88 MB

    dim3 blk(256);

    // 1. h = elu(emb[x] @ Wh + Wh_b)
    gemm2_k<0, 1, 1><<<dim3(4, 64), blk, 0, stream>>>(
        nullptr, x1, x2, emb, Wh_w, nullptr, nullptr, Wh_b,
        nullptr, nullptr, h, NROWS, 200, 200, 200, 200, 200);
    // 2. hP = [(h@W1 + b)*k1 | (h@W2)*k1 | h@Wf2 + Wf2_b]
    gemm2_k<1, 3, 0><<<dim3(10, 64), blk, 0, stream>>>(
        h, nullptr, nullptr, nullptr, W1_w, W2_w, Wf2_w, Wf2_b,
        bvec, cptr, hP, NROWS, 600, 200, 200, 200, 600);

    const bool big = (ws_size >= need_bytes);
    if (big) {
        // 3. attention partials + combine
        attn_part4_k<<<dim3(2048), blk, 0, stream>>>(h, hP, cptr, x1, x2, P, hsumP);
        attn_comb4_k<<<dim3(512), blk, 0, stream>>>(P, hsumP, x1, x2, sfw, sbw);
    } else {
        attn_k<<<dim3(1024), blk, 0, stream>>>(h, hP, cptr, x1, x2, sfw, sbw);
    }
    // 4. u = gate(s @ Wf1) fused (M = 4096 covers sfw|sbw)
    gemm2_k<0, 2, 0><<<dim3(4, 128), blk, 0, stream>>>(
        sfw, nullptr, nullptr, nullptr, Wf1_w, nullptr, nullptr, nullptr,
        h, hP, u, 2 * NROWS, 200, 200, 200, 200, 400);
    if (big) {
        // 5. v1 = elu(u @ Ws1 + b): k-split x4 -> P, combine
        gemm2_k<0, 0, 0><<<dim3(7, 64, 4), blk, 0, stream>>>(
            u, nullptr, nullptr, nullptr, Ws1_w, nullptr, nullptr, nullptr,
            nullptr, nullptr, P, NROWS, 400, 100, 400, 400, 400);
        v1comb_k<<<dim3(3200), blk, 0, stream>>>(P, Ws1_b, v1);
        // 6. atts = v1 @ Ws + Ws_b (k-split x4 -> P), fused with reduce -> bv
        gemm2_k<0, 0, 0><<<dim3(7, 64, 4), blk, 0, stream>>>(
            v1, nullptr, nullptr, nullptr, Ws_w, nullptr, nullptr, nullptr,
            nullptr, nullptr, P, NROWS, 400, 100, 400, 400, 400);
        bvcomb_k<<<dim3(16, 7), blk, 0, stream>>>(u, P, Ws_b, bv);
    } else {
        float* atts = P;   // fallback scratch
        gemm2_k<0, 1, 0><<<dim3(7, 64), blk, 0, stream>>>(
            u, nullptr, nullptr, nullptr, Ws1_w, nullptr, nullptr, Ws1_b,
            nullptr, nullptr, v1, NROWS, 400, 400, 400, 400, 400);
        gemm2_k<0, 0, 0><<<dim3(7, 64), blk, 0, stream>>>(
            v1, nullptr, nullptr, nullptr, Ws_w, nullptr, nullptr, Ws_b,
            nullptr, nullptr, atts, NROWS, 400, 400, 400, 400, 400);
        reduce_k<<<dim3(16, 7), blk, 0, stream>>>(u, atts, bv);
    }
    // 7-8. final MLP
    final1_part_k<<<dim3(32), blk, 0, stream>>>(bv, F1_w, partM);
    final2_k<<<dim3(8), blk, 0, stream>>>(partM, F1_b, F2_w, F2_b, y);
}

// Round 8
// 158.913 us; speedup vs baseline: 3.7932x; 1.0320x over previous
//
#include <hip/hip_runtime.h>
#include <hip/hip_bf16.h>
#include <math.h>

// Problem constants
#define B 8
#define L 128
#define D 200
#define NROWS 2048          // 2 sequences * B * L
#define PAD_ID 1
#define LOG2E 1.4426950408889634f

// ---------------- Tiled f32 GEMM, TM=32 x TN=64, 2x4 micro, reg-prefetch ------------
// WMODE: 0 = plain W[k*ldw+col]; 1 = proj3 (W0|W1p|W2p each stride 200)
// EMODE: 0 = (+bias if given); 1 = bias+ELU; 2 = ucomb gate; 3 = proj3 precompute
// GATHER: A row r = emb[ids(r)]
// blockIdx.z = k-split slice: koff = z*K, C += z*M*ldc (parts mode uses EMODE0,bias=0)
template<int WMODE, int EMODE, int GATHER>
__global__ __launch_bounds__(256)
void gemm2_k(const float* __restrict__ A,
             const int* __restrict__ x1, const int* __restrict__ x2,
             const float* __restrict__ emb,
             const float* __restrict__ W0, const float* __restrict__ W1p,
             const float* __restrict__ W2p, const float* __restrict__ bias,
             const float* __restrict__ aux1, const float* __restrict__ aux2,
             float* __restrict__ C, int M, int N, int K,
             int lda, int ldw, int ldc)
{
    __shared__ float As[16][34];
    __shared__ float Bs[16][68];
    const int koff = blockIdx.z * K;
    A += koff;
    if (WMODE == 0) { W0 += (size_t)koff * ldw; }
    else { W0 += koff * 200; W1p += koff * 200; W2p += koff * 200; }
    C += (size_t)blockIdx.z * M * ldc;

    const int row0 = blockIdx.y * 32, col0 = blockIdx.x * 64;
    const int tid = threadIdx.x;
    const int tx = tid & 15, ty = tid >> 4;

    float ra[2], rb[4];
    const int nK = (K + 15) >> 4;

    {
        const int kk = tid & 15;
        #pragma unroll
        for (int p = 0; p < 2; ++p) {
            int row = row0 + (tid >> 4) + p * 16;
            float v = 0.f;
            if (kk < K) {
                if (GATHER) { int id = (row < 1024) ? x1[row] : x2[row - 1024];
                              v = emb[id * lda + koff + kk]; }
                else v = A[row * lda + kk];
            }
            ra[p] = v;
        }
        const int nn = col0 + (tid & 63);
        #pragma unroll
        for (int p = 0; p < 4; ++p) {
            int kk2 = (tid >> 6) + p * 4;
            float v = 0.f;
            if (kk2 < K && nn < N) {
                if (WMODE == 1)
                    v = (nn < 200) ? W0[kk2 * 200 + nn]
                      : (nn < 400) ? W1p[kk2 * 200 + nn - 200]
                                   : W2p[kk2 * 200 + nn - 400];
                else v = W0[kk2 * ldw + nn];
            }
            rb[p] = v;
        }
    }

    float acc[2][4] = {};
    for (int kc = 0; kc < nK; ++kc) {
        __syncthreads();
        As[tid & 15][tid >> 4]      = ra[0];
        As[tid & 15][(tid >> 4)+16] = ra[1];
        #pragma unroll
        for (int p = 0; p < 4; ++p) Bs[(tid >> 6) + p * 4][tid & 63] = rb[p];
        __syncthreads();

        if (kc + 1 < nK) {
            const int k0 = (kc + 1) * 16;
            const int kk = k0 + (tid & 15);
            #pragma unroll
            for (int p = 0; p < 2; ++p) {
                int row = row0 + (tid >> 4) + p * 16;
                float v = 0.f;
                if (kk < K) {
                    if (GATHER) { int id = (row < 1024) ? x1[row] : x2[row - 1024];
                                  v = emb[id * lda + koff + kk]; }
                    else v = A[row * lda + kk];
                }
                ra[p] = v;
            }
            const int nn = col0 + (tid & 63);
            #pragma unroll
            for (int p = 0; p < 4; ++p) {
                int kk2 = k0 + (tid >> 6) + p * 4;
                float v = 0.f;
                if (kk2 < K && nn < N) {
                    if (WMODE == 1)
                        v = (nn < 200) ? W0[kk2 * 200 + nn]
                          : (nn < 400) ? W1p[kk2 * 200 + nn - 200]
                                       : W2p[kk2 * 200 + nn - 400];
                    else v = W0[kk2 * ldw + nn];
                }
                rb[p] = v;
            }
        }

        #pragma unroll
        for (int k = 0; k < 16; ++k) {
            float a0 = As[k][ty * 2], a1 = As[k][ty * 2 + 1];
            float w0 = Bs[k][tx * 4], w1 = Bs[k][tx * 4 + 1];
            float w2 = Bs[k][tx * 4 + 2], w3 = Bs[k][tx * 4 + 3];
            acc[0][0] = fmaf(a0, w0, acc[0][0]); acc[0][1] = fmaf(a0, w1, acc[0][1]);
            acc[0][2] = fmaf(a0, w2, acc[0][2]); acc[0][3] = fmaf(a0, w3, acc[0][3]);
            acc[1][0] = fmaf(a1, w0, acc[1][0]); acc[1][1] = fmaf(a1, w1, acc[1][1]);
            acc[1][2] = fmaf(a1, w2, acc[1][2]); acc[1][3] = fmaf(a1, w3, acc[1][3]);
        }
    }

    #pragma unroll
    for (int i = 0; i < 2; ++i) {
        const int row = row0 + ty * 2 + i;
        #pragma unroll
        for (int j = 0; j < 4; ++j) {
            const int col = col0 + tx * 4 + j;
            if (col >= N) continue;
            float v = acc[i][j];
            if (EMODE == 2) {
                const int sr = row & 2047, half = row >> 11;
                float g = v + aux2[sr * 600 + 400 + col];
                float f = 1.0f / (1.0f + __expf(-g));
                float s = A[row * lda + col];
                float hv = aux1[sr * 200 + col];
                C[sr * 400 + half * 200 + col] = f * hv + (1.f - f) * s;
            } else if (EMODE == 3) {
                const float k1 = 2.0f * LOG2E / aux2[0];
                if (col < 200)      v = (v + aux1[col]) * k1;
                else if (col < 400) v = v * k1;
                else                v += bias[col - 400];
                C[row * ldc + col] = v;
            } else {
                if (bias) v += bias[col];
                if (EMODE == 1) v = (v > 0.f) ? v : expm1f(v);
                C[row * ldc + col] = v;
            }
        }
    }
}

// ---------------- Combine kernels for k-split GEMM parts ----------------
// h = elu(sum4 P + Wh_b)
__global__ __launch_bounds__(256)
void hcomb_k(const float* __restrict__ P, const float* __restrict__ bias,
             float* __restrict__ h)
{
    const int idx = blockIdx.x * 256 + threadIdx.x;
    if (idx >= NROWS * 200) return;
    const int col = idx % 200;
    float s = P[idx] + P[idx + 409600] + P[idx + 819200] + P[idx + 1228800]
            + bias[col];
    h[idx] = (s > 0.f) ? s : expm1f(s);
}

// hP = proj3 precompute epilogue over sum4 parts
__global__ __launch_bounds__(256)
void p3comb_k(const float* __restrict__ P, const float* __restrict__ bvec,
              const float* __restrict__ Wf2_b, const float* __restrict__ cptr,
              float* __restrict__ hP)
{
    const int idx = blockIdx.x * 256 + threadIdx.x;
    if (idx >= NROWS * 600) return;
    const int col = idx % 600;
    float v = P[idx] + P[idx + 1228800] + P[idx + 2 * 1228800] + P[idx + 3 * 1228800];
    const float k1 = 2.0f * LOG2E / cptr[0];
    if (col < 200)      v = (v + bvec[col]) * k1;
    else if (col < 400) v = v * k1;
    else                v += Wf2_b[col - 400];
    hP[idx] = v;
}

// u = gate(sum4 P + hf2) applied to h/s
__global__ __launch_bounds__(256)
void ugate_k(const float* __restrict__ P, const float* __restrict__ h,
             const float* __restrict__ hP, const float* __restrict__ sfw,
             float* __restrict__ u)
{
    const int idx = blockIdx.x * 256 + threadIdx.x;
    if (idx >= 2 * NROWS * 200) return;
    const int row = idx / 200, col = idx - row * 200;
    const int sr = row & 2047, half = row >> 11;
    float g = P[idx] + P[idx + 819200] + P[idx + 2 * 819200] + P[idx + 3 * 819200]
            + hP[sr * 600 + 400 + col];
    float f = 1.0f / (1.0f + __expf(-g));
    float s = sfw[idx];
    float hv = h[sr * 200 + col];
    u[sr * 400 + half * 200 + col] = f * hv + (1.f - f) * s;
}

// ---------------- Attention partial: 4 queries x 32 keys per block ----------------
__global__ __launch_bounds__(256)
void attn_part4_k(const float* __restrict__ h, const float* __restrict__ hP,
                  const float* __restrict__ cptr,
                  const int* __restrict__ x1, const int* __restrict__ x2,
                  float* __restrict__ part, float* __restrict__ hsumP)
{
    const int blk = blockIdx.x;          // 0..2047
    const int jq  = blk & 3;
    const int qc  = (blk >> 2) & 31;
    const int sb  = blk >> 7;            // 0..15
    const int i0  = qc * 4;
    const int base = sb * 128;
    const int j0 = jq * 32, j1 = j0 + 32;
    const int d = threadIdx.x;
    const int* ids = (sb < 8) ? x1 : x2;
    const int loc0 = (sb & 7) * 128;

    const float cval = cptr[0];
    const float mcoef = -2.0f * cval * LOG2E;

    const unsigned long long km =
        __ballot(ids[loc0 + j0 + (threadIdx.x & 31)] == PAD_ID);

    float pq[4];
    #pragma unroll
    for (int q = 0; q < 4; ++q)
        pq[q] = (d < D) ? hP[(base + i0 + q) * 600 + d] : 0.f;

    float lf[4] = {}, af[4] = {}, lb[4] = {}, ab[4] = {};
    float hsum = 0.f;

    auto sc = [&](float p, float h2k) -> float {
        float e2 = __builtin_amdgcn_exp2f(p + h2k);
        return __builtin_amdgcn_exp2f(mcoef * __builtin_amdgcn_rcpf(e2 + 1.0f));
    };
    auto ldrow = [&](int j, float& h2k, float& hj) {
        h2k = 0.f; hj = 0.f;
        if (d < D) {
            h2k = hP[(base + j) * 600 + 200 + d];
            hj  = h[(base + j) * 200 + d];
        }
    };

    const int aEnd = (i0 < j1) ? i0 : j1;
    for (int j = j0; j < aEnd; j += 2) {
        float h2a, ha, h2b, hb;
        ldrow(j, h2a, ha); ldrow(j + 1, h2b, hb);
        hsum += ha + hb;
        if (!((km >> (j - j0)) & 1ull)) {
            #pragma unroll
            for (int q = 0; q < 4; ++q) {
                float w = sc(pq[q], h2a);
                lb[q] += w; ab[q] = fmaf(w, ha, ab[q]);
            }
        }
        if (!((km >> (j + 1 - j0)) & 1ull)) {
            #pragma unroll
            for (int q = 0; q < 4; ++q) {
                float w = sc(pq[q], h2b);
                lb[q] += w; ab[q] = fmaf(w, hb, ab[q]);
            }
        }
    }
    if (i0 >= j0 && i0 < j1) {
        #pragma unroll
        for (int jj = 0; jj < 4; ++jj) {
            const int j = i0 + jj;
            float h2a, ha;
            ldrow(j, h2a, ha);
            hsum += ha;
            if (!((km >> (j - j0)) & 1ull)) {
                #pragma unroll
                for (int q = 0; q < 4; ++q) {
                    if (jj == q) continue;
                    float w = sc(pq[q], h2a);
                    if (jj > q) { lf[q] += w; af[q] = fmaf(w, ha, af[q]); }
                    else        { lb[q] += w; ab[q] = fmaf(w, ha, ab[q]); }
                }
            }
        }
    }
    const int cs = (i0 + 4 > j0) ? i0 + 4 : j0;
    for (int j = cs; j < j1; j += 2) {
        float h2a, ha, h2b, hb;
        ldrow(j, h2a, ha); ldrow(j + 1, h2b, hb);
        hsum += ha + hb;
        if (!((km >> (j - j0)) & 1ull)) {
            #pragma unroll
            for (int q = 0; q < 4; ++q) {
                float w = sc(pq[q], h2a);
                lf[q] += w; af[q] = fmaf(w, ha, af[q]);
            }
        }
        if (!((km >> (j + 1 - j0)) & 1ull)) {
            #pragma unroll
            for (int q = 0; q < 4; ++q) {
                float w = sc(pq[q], h2b);
                lf[q] += w; af[q] = fmaf(w, hb, af[q]);
            }
        }
    }

    if (d < D) {
        float* pp = part + (size_t)blk * 3200;   // [blk][16][200]
        #pragma unroll
        for (int q = 0; q < 4; ++q) {
            pp[(q * 4 + 0) * 200 + d] = lf[q];
            pp[(q * 4 + 1) * 200 + d] = af[q];
            pp[(q * 4 + 2) * 200 + d] = lb[q];
            pp[(q * 4 + 3) * 200 + d] = ab[q];
        }
        hsumP[(jq * 16 + sb) * 200 + d] = hsum;
    }
}

__global__ __launch_bounds__(256)
void attn_comb4_k(const float* __restrict__ part, const float* __restrict__ hsumP,
                  const int* __restrict__ x1, const int* __restrict__ x2,
                  float* __restrict__ s_fw, float* __restrict__ s_bw)
{
    const int g = blockIdx.x;            // 0..511 = sb*32 + qc
    const int sb = g >> 5, qc = g & 31;
    const int i0 = qc * 4, base = sb * 128;
    const int d = threadIdx.x;
    if (d >= D) return;
    const int* ids = (sb < 8) ? x1 : x2;
    const int loc0 = (sb & 7) * 128;
    float hs = 0.f;
    #pragma unroll
    for (int jq = 0; jq < 4; ++jq) hs += hsumP[(jq * 16 + sb) * 200 + d];
    const float fb = hs * (1.0f / 128.0f);
    #pragma unroll
    for (int q = 0; q < 4; ++q) {
        const bool mi = (ids[loc0 + i0 + q] == PAD_ID);
        float lf = 0.f, af = 0.f, lb = 0.f, ab = 0.f;
        #pragma unroll
        for (int jq = 0; jq < 4; ++jq) {
            const float* pp = part + ((size_t)(sb * 128 + qc * 4 + jq)) * 3200
                                   + (q * 4) * 200;
            lf += pp[d]; af += pp[200 + d]; lb += pp[400 + d]; ab += pp[600 + d];
        }
        s_fw[(base + i0 + q) * 200 + d] = (!mi && lf > 0.f) ? af / lf : fb;
        s_bw[(base + i0 + q) * 200 + d] = (!mi && lb > 0.f) ? ab / lb : fb;
    }
}

// ---------------- Fallback monolithic attention ----------------
__global__ __launch_bounds__(256)
void attn_k(const float* __restrict__ h, const float* __restrict__ hP,
            const float* __restrict__ cptr,
            const int* __restrict__ x1, const int* __restrict__ x2,
            float* __restrict__ s_fw, float* __restrict__ s_bw)
{
    const int blk = blockIdx.x;
    const int sb  = blk >> 6;
    const int i0  = (blk & 63) * 2;
    const int base = sb * 128;
    const int d = threadIdx.x;
    const int* ids = (sb < 8) ? x1 : x2;
    const int loc0 = (sb & 7) * 128;

    const float cval = cptr[0];
    const float mcoef = -2.0f * cval * LOG2E;

    const bool mi0 = (ids[loc0 + i0] == PAD_ID);
    const bool mi1 = (ids[loc0 + i0 + 1] == PAD_ID);
    float pq0 = 0.f, pq1 = 0.f;
    if (d < D) {
        pq0 = hP[(base + i0) * 600 + d];
        pq1 = hP[(base + i0 + 1) * 600 + d];
    }

    float lf0 = 0.f, af0 = 0.f, lb0 = 0.f, ab0 = 0.f;
    float lf1 = 0.f, af1 = 0.f, lb1 = 0.f, ab1 = 0.f;
    float hsum = 0.f;

    auto sc = [&](float pq, float h2k) -> float {
        float e2 = __builtin_amdgcn_exp2f(pq + h2k);
        return __builtin_amdgcn_exp2f(mcoef * __builtin_amdgcn_rcpf(e2 + 1.0f));
    };
    auto ldrow = [&](int j, float& h2k, float& hj) {
        h2k = 0.f; hj = 0.f;
        if (d < D) {
            h2k = hP[(base + j) * 600 + 200 + d];
            hj  = h[(base + j) * 200 + d];
        }
    };

    for (int j = 0; j + 1 < i0; j += 2) {
        float h2a, ha, h2b, hb;
        ldrow(j, h2a, ha); ldrow(j + 1, h2b, hb);
        hsum += ha + hb;
        if (ids[loc0 + j] != PAD_ID) {
            float w0 = sc(pq0, h2a), w1 = sc(pq1, h2a);
            lb0 += w0; ab0 = fmaf(w0, ha, ab0);
            lb1 += w1; ab1 = fmaf(w1, ha, ab1);
        }
        if (ids[loc0 + j + 1] != PAD_ID) {
            float w0 = sc(pq0, h2b), w1 = sc(pq1, h2b);
            lb0 += w0; ab0 = fmaf(w0, hb, ab0);
            lb1 += w1; ab1 = fmaf(w1, hb, ab1);
        }
    }
    {
        float h2a, ha, h2b, hb;
        ldrow(i0, h2a, ha); ldrow(i0 + 1, h2b, hb);
        hsum += ha + hb;
        if (ids[loc0 + i0] != PAD_ID) {
            float w1 = sc(pq1, h2a);
            lb1 += w1; ab1 = fmaf(w1, ha, ab1);
        }
        if (ids[loc0 + i0 + 1] != PAD_ID) {
            float w0 = sc(pq0, h2b);
            lf0 += w0; af0 = fmaf(w0, hb, af0);
        }
    }
    for (int j = i0 + 2; j < 128; j += 2) {
        float h2a, ha, h2b, hb;
        ldrow(j, h2a, ha); ldrow(j + 1, h2b, hb);
        hsum += ha + hb;
        if (ids[loc0 + j] != PAD_ID) {
            float w0 = sc(pq0, h2a), w1 = sc(pq1, h2a);
            lf0 += w0; af0 = fmaf(w0, ha, af0);
            lf1 += w1; af1 = fmaf(w1, ha, af1);
        }
        if (ids[loc0 + j + 1] != PAD_ID) {
            float w0 = sc(pq0, h2b), w1 = sc(pq1, h2b);
            lf0 += w0; af0 = fmaf(w0, hb, af0);
            lf1 += w1; af1 = fmaf(w1, hb, af1);
        }
    }

    if (d < D) {
        const float fb = hsum * (1.0f / 128.0f);
        s_fw[(base + i0) * D + d]     = (!mi0 && lf0 > 0.f) ? (af0 / lf0) : fb;
        s_bw[(base + i0) * D + d]     = (!mi0 && lb0 > 0.f) ? (ab0 / lb0) : fb;
        s_fw[(base + i0 + 1) * D + d] = (!mi1 && lf1 > 0.f) ? (af1 / lf1) : fb;
        s_bw[(base + i0 + 1) * D + d] = (!mi1 && lb1 > 0.f) ? (ab1 / lb1) : fb;
    }
}

// ---------------- v1 = elu(sum of 4 k-split parts + bias) ----------------
__global__ __launch_bounds__(256)
void v1comb_k(const float* __restrict__ P, const float* __restrict__ bias,
              float* __restrict__ v1)
{
    const int idx = blockIdx.x * 256 + threadIdx.x;
    if (idx >= NROWS * 400) return;
    const int col = idx % 400;
    float s = P[idx] + P[idx + 819200] + P[idx + 2 * 819200] + P[idx + 3 * 819200]
            + bias[col];
    v1[idx] = (s > 0.f) ? s : expm1f(s);
}

// ---------------- bvP[lz] = partial sum_l u * (sum4 Ws parts + Ws_b) ----------------
// grid (16, 7, 4); block 256 = 64 cols x 4 row-groups of 8
__global__ __launch_bounds__(256)
void bvcomb_k(const float* __restrict__ u, const float* __restrict__ P,
              const float* __restrict__ bias, float* __restrict__ bvP)
{
    __shared__ float red[4][64];
    const int sb = blockIdx.x, nt = blockIdx.y, lz = blockIdx.z;
    const int tid = threadIdx.x;
    const int nl = tid & 63, lg = tid >> 6;
    const int n = nt * 64 + nl;
    float acc = 0.f;
    if (n < 400) {
        const float bn = bias[n];
        const int r0 = sb * 128 + lz * 32 + lg * 8;
        for (int l = 0; l < 8; ++l) {
            const int idx = (r0 + l) * 400 + n;
            float a = P[idx] + P[idx + 819200] + P[idx + 2 * 819200]
                    + P[idx + 3 * 819200] + bn;
            acc = fmaf(u[idx], a, acc);
        }
    }
    red[lg][nl] = acc;
    __syncthreads();
    if (tid < 64 && n < 400)
        bvP[lz * 6400 + sb * 400 + n] = red[0][nl] + red[1][nl] + red[2][nl] + red[3][nl];
}

// ---------------- Fallback reduce (writes bvP slice 0) ----------------
__global__ __launch_bounds__(256)
void reduce_k(const float* __restrict__ u, const float* __restrict__ atts,
              float* __restrict__ bv)
{
    __shared__ float p[4][64];
    const int sb = blockIdx.x, nt = blockIdx.y;
    const int tid = threadIdx.x;
    const int nl = tid & 63, lg = tid >> 6;
    const int n = nt * 64 + nl;
    float acc = 0.f;
    if (n < 400) {
        const int r0 = sb * 128 + lg * 32;
        #pragma unroll 4
        for (int l = 0; l < 32; ++l)
            acc = fmaf(u[(r0 + l) * 400 + n], atts[(r0 + l) * 400 + n], acc);
    }
    p[lg][nl] = acc;
    __syncthreads();
    if (tid < 64 && n < 400)
        bv[sb * 400 + n] = p[0][nl] + p[1][nl] + p[2][nl] + p[3][nl];
}

// ---------------- Final MLP ----------------
#define KT 50
template<int NS>
__global__ __launch_bounds__(256)
void final1_part_k(const float* __restrict__ bvP, const float* __restrict__ F1w,
                   float* __restrict__ part)
{
    __shared__ float feats[8][KT];
    const int bid = blockIdx.x;
    const int seg = bid >> 3;
    const int kr0 = (bid & 7) * KT;
    const int tid = threadIdx.x;
    for (int idx = tid; idx < 8 * KT; idx += 256) {
        int b = idx / KT, kk = idx - b * KT;
        float cv = 0.f, rv = 0.f;
        #pragma unroll
        for (int z = 0; z < NS; ++z) {
            cv += bvP[z * 6400 + b * 400 + kr0 + kk];
            rv += bvP[z * 6400 + (8 + b) * 400 + kr0 + kk];
        }
        feats[b][kk] = (seg == 0) ? cv : (seg == 1) ? rv
                     : (seg == 2) ? (cv - rv) : (cv * rv);
    }
    __syncthreads();
    const int n = tid;
    if (n >= 200) return;
    const int kbase = seg * 400 + kr0;
    float acc[8] = {};
    #pragma unroll 5
    for (int kk = 0; kk < KT; ++kk) {
        float w = F1w[(kbase + kk) * 200 + n];
        #pragma unroll
        for (int b = 0; b < 8; ++b)
            acc[b] = fmaf(feats[b][kk], w, acc[b]);
    }
    #pragma unroll
    for (int b = 0; b < 8; ++b)
        part[(bid * 8 + b) * 200 + n] = acc[b];
}

__global__ __launch_bounds__(256)
void final2_k(const float* __restrict__ part, const float* __restrict__ F1b,
              const float* __restrict__ F2w, const float* __restrict__ F2b,
              float* __restrict__ y)
{
    __shared__ float red[256];
    const int b = blockIdx.x, tid = threadIdx.x;
    float v = 0.f;
    if (tid < 200) {
        float s = F1b[tid];
        #pragma unroll 8
        for (int t = 0; t < 32; ++t)
            s += part[(t * 8 + b) * 200 + tid];
        v = fmaxf(s, 0.f) * F2w[tid];
    }
    red[tid] = v;
    __syncthreads();
    for (int off = 128; off; off >>= 1) {
        if (tid < off) red[tid] += red[tid + off];
        __syncthreads();
    }
    if (tid == 0) y[b] = red[0] + F2b[0];
}

extern "C" void kernel_launch(void* const* d_in, const int* in_sizes, int n_in,
                              void* d_out, int out_size, void* d_ws, size_t ws_size,
                              hipStream_t stream)
{
    const int*   x1    = (const int*)d_in[0];
    const int*   x2    = (const int*)d_in[1];
    const float* emb   = (const float*)d_in[2];
    const float* Wh_w  = (const float*)d_in[3];
    const float* Wh_b  = (const float*)d_in[4];
    const float* W1_w  = (const float*)d_in[5];
    const float* W2_w  = (const float*)d_in[6];
    const float* bvec  = (const float*)d_in[7];
    const float* cptr  = (const float*)d_in[8];
    const float* Wf1_w = (const float*)d_in[9];
    const float* Wf2_w = (const float*)d_in[10];
    const float* Wf2_b = (const float*)d_in[11];
    const float* Ws1_w = (const float*)d_in[12];
    const float* Ws1_b = (const float*)d_in[13];
    const float* Ws_w  = (const float*)d_in[14];
    const float* Ws_b  = (const float*)d_in[15];
    const float* F1_w  = (const float*)d_in[16];
    const float* F1_b  = (const float*)d_in[17];
    const float* F2_w  = (const float*)d_in[18];
    const float* F2_b  = (const float*)d_in[19];
    float* y = (float*)d_out;

    float* ws = (float*)d_ws;
    float* h     = ws;                    // 409600
    float* hP    = h     + 409600;        // 1228800 ((h1+b)*k1 | h2*k1 | hf2)
    float* sfw   = hP    + 1228800;       // 409600
    float* sbw   = sfw   + 409600;        // 409600 (contiguous after sfw)
    float* u     = sbw   + 409600;        // 819200
    float* v1    = u     + 819200;        // 819200
    float* bvP   = v1    + 819200;        // 4*6400
    float* partM = bvP   + 25600;         // 51200
    float* hsumP = partM + 51200;         // 12800
    float* P     = hsumP + 12800;         // 6553600 (shared parts buffer)
    const size_t need_bytes = (size_t)(10739200) * 4;   // ~42.96 MB

    dim3 blk(256);
    const bool big = (ws_size >= need_bytes);

    if (big) {
        // 1. h parts (k-split x4, K=50) + combine(elu + bias)
        gemm2_k<0, 0, 1><<<dim3(4, 64, 4), blk, 0, stream>>>(
            nullptr, x1, x2, emb, Wh_w, nullptr, nullptr, nullptr,
            nullptr, nullptr, P, NROWS, 200, 50, 200, 200, 200);
        hcomb_k<<<dim3(1600), blk, 0, stream>>>(P, Wh_b, h);
        // 2. proj3 parts (k-split x4) + combine(precompute epilogue)
        gemm2_k<1, 0, 0><<<dim3(10, 64, 4), blk, 0, stream>>>(
            h, nullptr, nullptr, nullptr, W1_w, W2_w, Wf2_w, nullptr,
            nullptr, nullptr, P, NROWS, 600, 50, 200, 200, 600);
        p3comb_k<<<dim3(4800), blk, 0, stream>>>(P, bvec, Wf2_b, cptr, hP);
        // 3. attention partials + combine
        attn_part4_k<<<dim3(2048), blk, 0, stream>>>(h, hP, cptr, x1, x2, P, hsumP);
        attn_comb4_k<<<dim3(512), blk, 0, stream>>>(P, hsumP, x1, x2, sfw, sbw);
        // 4. Wf1 parts (M=4096, k-split x4) + gate combine -> u
        gemm2_k<0, 0, 0><<<dim3(4, 128, 4), blk, 0, stream>>>(
            sfw, nullptr, nullptr, nullptr, Wf1_w, nullptr, nullptr, nullptr,
            nullptr, nullptr, P, 2 * NROWS, 200, 50, 200, 200, 200);
        ugate_k<<<dim3(3200), blk, 0, stream>>>(P, h, hP, sfw, u);
        // 5. Ws1 parts (k-split x4, K=100) + combine(elu)
        gemm2_k<0, 0, 0><<<dim3(7, 64, 4), blk, 0, stream>>>(
            u, nullptr, nullptr, nullptr, Ws1_w, nullptr, nullptr, nullptr,
            nullptr, nullptr, P, NROWS, 400, 100, 400, 400, 400);
        v1comb_k<<<dim3(3200), blk, 0, stream>>>(P, Ws1_b, v1);
        // 6. Ws parts (k-split x4) + fused reduce -> bvP (l-split x4)
        gemm2_k<0, 0, 0><<<dim3(7, 64, 4), blk, 0, stream>>>(
            v1, nullptr, nullptr, nullptr, Ws_w, nullptr, nullptr, nullptr,
            nullptr, nullptr, P, NROWS, 400, 100, 400, 400, 400);
        bvcomb_k<<<dim3(16, 7, 4), blk, 0, stream>>>(u, P, Ws_b, bvP);
        // 7-8. final MLP
        final1_part_k<4><<<dim3(32), blk, 0, stream>>>(bvP, F1_w, partM);
        final2_k<<<dim3(8), blk, 0, stream>>>(partM, F1_b, F2_w, F2_b, y);
    } else {
        gemm2_k<0, 1, 1><<<dim3(4, 64), blk, 0, stream>>>(
            nullptr, x1, x2, emb, Wh_w, nullptr, nullptr, Wh_b,
            nullptr, nullptr, h, NROWS, 200, 200, 200, 200, 200);
        gemm2_k<1, 3, 0><<<dim3(10, 64), blk, 0, stream>>>(
            h, nullptr, nullptr, nullptr, W1_w, W2_w, Wf2_w, Wf2_b,
            bvec, cptr, hP, NROWS, 600, 200, 200, 200, 600);
        attn_k<<<dim3(1024), blk, 0, stream>>>(h, hP, cptr, x1, x2, sfw, sbw);
        gemm2_k<0, 2, 0><<<dim3(4, 128), blk, 0, stream>>>(
            sfw, nullptr, nullptr, nullptr, Wf1_w, nullptr, nullptr, nullptr,
            h, hP, u, 2 * NROWS, 200, 200, 200, 200, 400);
        float* atts = P;
        gemm2_k<0, 1, 0><<<dim3(7, 64), blk, 0, stream>>>(
            u, nullptr, nullptr, nullptr, Ws1_w, nullptr, nullptr, Ws1_b,
            nullptr, nullptr, v1, NROWS, 400, 400, 400, 400, 400);
        gemm2_k<0, 0, 0><<<dim3(7, 64), blk, 0, stream>>>(
            v1, nullptr, nullptr, nullptr, Ws_w, nullptr, nullptr, Ws_b,
            nullptr, nullptr, atts, NROWS, 400, 400, 400, 400, 400);
        reduce_k<<<dim3(16, 7), blk, 0, stream>>>(u, atts, bvP);
        final1_part_k<1><<<dim3(32), blk, 0, stream>>>(bvP, F1_w, partM);
        final2_k<<<dim3(8), blk, 0, stream>>>(partM, F1_b, F2_w, F2_b, y);
    }
}